// Round 2
// baseline (566.362 us; speedup 1.0000x reference)
//
#include <hip/hip_runtime.h>
#include <hip/hip_bf16.h>

// Problem: B=1, N=128, C=128, H=8, D=16. SCALE = 0.25.
// All inputs/outputs are float32 (per reference setup_inputs dtypes).
// Workspace (fp32): e_ln[16384*128] qkv_in[16384*384] qkv_out[16384*384]
//   eg_in[16384*16] eg_out[16384*16] va[16384*256]  => ~77.6 MB

#define NPOS 16384   // N*N
#define CDIM 128

// ---------------- LayerNorm: e -> e_ln (fp32) ----------------
__global__ __launch_bounds__(128) void ln_kernel(
    const float* __restrict__ e,
    const float* __restrict__ w,
    const float* __restrict__ b,
    float* __restrict__ out)
{
    const int row = blockIdx.x;
    const int t = threadIdx.x;
    float x = e[(size_t)row * CDIM + t];
    float s = x, s2 = x * x;
    #pragma unroll
    for (int off = 1; off < 64; off <<= 1) {
        s  += __shfl_xor(s,  off, 64);
        s2 += __shfl_xor(s2, off, 64);
    }
    __shared__ float sh[4];
    if ((t & 63) == 0) { sh[(t >> 6) * 2] = s; sh[(t >> 6) * 2 + 1] = s2; }
    __syncthreads();
    float sum = sh[0] + sh[2], sumsq = sh[1] + sh[3];
    float m = sum * (1.f / 128.f);
    float v = sumsq * (1.f / 128.f) - m * m;
    float sc = rsqrtf(v + 1e-5f);
    out[(size_t)row * CDIM + t] = (x - m) * sc * w[t] + b[t];
}

// ---------------- Generic tiled GEMM: C = A @ B + bias (all fp32) ----------------
// A: M x K row-major, B: K x N row-major, C: M x N. BM=BN=64, BK=32, 256 thr.
// M % 64 == 0, K % 32 == 0 assumed; N guarded.
__global__ __launch_bounds__(256) void gemm_kernel(
    const float* __restrict__ A,
    const float* __restrict__ B,
    const float* __restrict__ bias,
    float* __restrict__ Cout,
    int M, int N, int K)
{
    __shared__ float As[64][33];
    __shared__ float Bs[32][65];
    const int t  = threadIdx.x;
    const int bm = blockIdx.x;
    const int bn = blockIdx.y;
    const int tx = t & 15;   // col group
    const int ty = t >> 4;   // row group

    float acc[4][4];
    #pragma unroll
    for (int r = 0; r < 4; ++r)
        #pragma unroll
        for (int c = 0; c < 4; ++c) acc[r][c] = 0.f;

    for (int k0 = 0; k0 < K; k0 += 32) {
        #pragma unroll
        for (int l = 0; l < 8; ++l) {
            int idx = t + l * 256;            // 0..2047
            int row = idx >> 5, kk = idx & 31;
            As[row][kk] = A[(size_t)(bm * 64 + row) * K + k0 + kk];
        }
        #pragma unroll
        for (int l = 0; l < 8; ++l) {
            int idx = t + l * 256;
            int kr = idx >> 6, col = idx & 63;
            int gcol = bn * 64 + col;
            Bs[kr][col] = (gcol < N) ? B[(size_t)(k0 + kr) * N + gcol] : 0.f;
        }
        __syncthreads();
        #pragma unroll
        for (int kk = 0; kk < 32; ++kk) {
            float a[4], bb[4];
            #pragma unroll
            for (int r = 0; r < 4; ++r) a[r] = As[ty * 4 + r][kk];
            #pragma unroll
            for (int c = 0; c < 4; ++c) bb[c] = Bs[kk][tx * 4 + c];
            #pragma unroll
            for (int r = 0; r < 4; ++r)
                #pragma unroll
                for (int c = 0; c < 4; ++c) acc[r][c] += a[r] * bb[c];
        }
        __syncthreads();
    }

    #pragma unroll
    for (int r = 0; r < 4; ++r) {
        int row = bm * 64 + ty * 4 + r;
        #pragma unroll
        for (int c = 0; c < 4; ++c) {
            int col = bn * 64 + tx * 4 + c;
            if (col < N) {
                Cout[(size_t)row * N + col] = acc[r][c] + bias[col];
            }
        }
    }
}

// ---------------- Fused triangle attention (both branches) ----------------
// grid: (j=128, h=8, br=2), block 256.
// in  (br=0): S[i,k] = sum_d Q[i,j,d,h]*K[j,k,d,h] + eg[i*128+k, h] + mask[i*128+k]
// out (br=1): S[i,k] = sum_d Q[i,j,d,h]*K[k,j,d,h] + eg[k*128+i, h] + mask[k*128+i]
// softmax over k, multiply gate = sigmoid(eg[r2, 8+h] + mask[r2]),
// Va[i,d] = sum_k A[i,k] * V[krow(k), d, h];  write va[(i*128+j)*256 + d*16 + br*8 + h]
__global__ __launch_bounds__(256) void attn_kernel(
    const float* __restrict__ qkv_in, const float* __restrict__ qkv_out,
    const float* __restrict__ eg_in,  const float* __restrict__ eg_out,
    const float* __restrict__ mask,
    float* __restrict__ va)
{
    const int j  = blockIdx.x;
    const int h  = blockIdx.y;
    const int br = blockIdx.z;
    const float* __restrict__ qkv = br ? qkv_out : qkv_in;
    const float* __restrict__ eg  = br ? eg_out  : eg_in;
    const int t = threadIdx.x;

    __shared__ float Qs[128][17];
    __shared__ float Ks[128][17];
    __shared__ float Vs[128][17];
    __shared__ float Ss[32][130];

    // stage Q, K, V slices (128 x 16 each)
    for (int idx = t; idx < 2048; idx += 256) {
        int r = idx >> 4, d = idx & 15;
        int qrow = r * 128 + j;                          // Q[i=r, j]
        int krow = br ? (r * 128 + j) : (j * 128 + r);   // K/V row
        Qs[r][d] = qkv[(size_t)qrow * 384 +       d * 8 + h] * 0.25f;
        Ks[r][d] = qkv[(size_t)krow * 384 + 128 + d * 8 + h];
        Vs[r][d] = qkv[(size_t)krow * 384 + 256 + d * 8 + h];
    }
    __syncthreads();

    const int r   = t >> 3;   // 0..31 (row within chunk)
    const int sub = t & 7;

    for (int ic0 = 0; ic0 < 128; ic0 += 32) {
        const int i = ic0 + r;
        float qreg[16];
        #pragma unroll
        for (int d = 0; d < 16; ++d) qreg[d] = Qs[i][d];

        // scores
        for (int kk = 0; kk < 16; ++kk) {
            int k = sub + kk * 8;
            float s = 0.f;
            #pragma unroll
            for (int d = 0; d < 16; ++d) s += qreg[d] * Ks[k][d];
            int r2 = br ? (k * 128 + i) : (i * 128 + k);
            s += eg[(size_t)r2 * 16 + h] + mask[r2];
            Ss[r][k] = s;
        }
        __syncthreads();

        // softmax over k + gate, rows handled by threads 0..31
        if (t < 32) {
            const int rr = t;
            const int ii = ic0 + rr;
            float mx = -1e30f;
            for (int k = 0; k < 128; ++k) mx = fmaxf(mx, Ss[rr][k]);
            float sum = 0.f;
            for (int k = 0; k < 128; ++k) {
                float p = __expf(Ss[rr][k] - mx);
                Ss[rr][k] = p;
                sum += p;
            }
            float inv = 1.f / sum;
            for (int k = 0; k < 128; ++k) {
                int r2 = br ? (k * 128 + ii) : (ii * 128 + k);
                float g = eg[(size_t)r2 * 16 + 8 + h] + mask[r2];
                float gate = 1.f / (1.f + __expf(-g));
                Ss[rr][k] *= inv * gate;
            }
        }
        __syncthreads();

        // Va: two d's per thread
        {
            const int d0 = sub * 2;
            float a0 = 0.f, a1 = 0.f;
            for (int k = 0; k < 128; ++k) {
                float p = Ss[r][k];
                a0 += p * Vs[k][d0];
                a1 += p * Vs[k][d0 + 1];
            }
            size_t base = ((size_t)(i * 128 + j)) * 256 + br * 8 + h;
            va[base +  d0      * 16] = a0;
            va[base + (d0 + 1) * 16] = a1;
        }
        __syncthreads();
    }
}

extern "C" void kernel_launch(void* const* d_in, const int* in_sizes, int n_in,
                              void* d_out, int out_size, void* d_ws, size_t ws_size,
                              hipStream_t stream) {
    const float* e        = (const float*)d_in[0];
    const float* mask     = (const float*)d_in[1];
    const float* ln_w     = (const float*)d_in[2];
    const float* ln_b     = (const float*)d_in[3];
    const float* w_qkv_in = (const float*)d_in[4];
    const float* b_qkv_in = (const float*)d_in[5];
    const float* w_eg_in  = (const float*)d_in[6];
    const float* b_eg_in  = (const float*)d_in[7];
    const float* w_qkv_o  = (const float*)d_in[8];
    const float* b_qkv_o  = (const float*)d_in[9];
    const float* w_eg_o   = (const float*)d_in[10];
    const float* b_eg_o   = (const float*)d_in[11];
    const float* w_o      = (const float*)d_in[12];
    const float* b_o      = (const float*)d_in[13];
    float* out = (float*)d_out;

    float* ws      = (float*)d_ws;
    float* e_ln    = ws;                               // 16384*128
    float* qkv_i   = e_ln  + (size_t)NPOS * 128;       // 16384*384
    float* qkv_o   = qkv_i + (size_t)NPOS * 384;       // 16384*384
    float* eg_i    = qkv_o + (size_t)NPOS * 384;       // 16384*16
    float* eg_o    = eg_i  + (size_t)NPOS * 16;        // 16384*16
    float* va      = eg_o  + (size_t)NPOS * 16;        // 16384*256

    ln_kernel<<<NPOS, 128, 0, stream>>>(e, ln_w, ln_b, e_ln);

    gemm_kernel<<<dim3(NPOS / 64, 6), 256, 0, stream>>>(
        e_ln, w_qkv_in, b_qkv_in, qkv_i, NPOS, 384, 128);
    gemm_kernel<<<dim3(NPOS / 64, 6), 256, 0, stream>>>(
        e_ln, w_qkv_o, b_qkv_o, qkv_o, NPOS, 384, 128);
    gemm_kernel<<<dim3(NPOS / 64, 1), 256, 0, stream>>>(
        e_ln, w_eg_in, b_eg_in, eg_i, NPOS, 16, 128);
    gemm_kernel<<<dim3(NPOS / 64, 1), 256, 0, stream>>>(
        e_ln, w_eg_o, b_eg_o, eg_o, NPOS, 16, 128);

    attn_kernel<<<dim3(128, 8, 2), 256, 0, stream>>>(
        qkv_i, qkv_o, eg_i, eg_o, mask, va);

    gemm_kernel<<<dim3(NPOS / 64, 2), 256, 0, stream>>>(
        va, w_o, b_o, out, NPOS, 128, 256);
}

// Round 3
// 325.228 us; speedup vs baseline: 1.7414x; 1.7414x over previous
//
#include <hip/hip_runtime.h>
#include <hip/hip_bf16.h>

// Problem: B=1, N=128, C=128, H=8, D=16. SCALE = 0.25. All I/O fp32.
// ws: e_ln[16384*128] (later aliased by E/G tables) qkv_in[16384*384]
//     qkv_out[16384*384] eg_in[16384*16] eg_out[16384*16] va[16384*256]

#define NPOS 16384   // N*N
#define CDIM 128

// ---------------- LayerNorm: e -> e_ln (fp32) ----------------
__global__ __launch_bounds__(128) void ln_kernel(
    const float* __restrict__ e,
    const float* __restrict__ w,
    const float* __restrict__ b,
    float* __restrict__ out)
{
    const int row = blockIdx.x;
    const int t = threadIdx.x;
    float x = e[(size_t)row * CDIM + t];
    float s = x, s2 = x * x;
    #pragma unroll
    for (int off = 1; off < 64; off <<= 1) {
        s  += __shfl_xor(s,  off, 64);
        s2 += __shfl_xor(s2, off, 64);
    }
    __shared__ float sh[4];
    if ((t & 63) == 0) { sh[(t >> 6) * 2] = s; sh[(t >> 6) * 2 + 1] = s2; }
    __syncthreads();
    float sum = sh[0] + sh[2], sumsq = sh[1] + sh[3];
    float m = sum * (1.f / 128.f);
    float v = sumsq * (1.f / 128.f) - m * m;
    float sc = rsqrtf(v + 1e-5f);
    out[(size_t)row * CDIM + t] = (x - m) * sc * w[t] + b[t];
}

// ---------------- Generic tiled GEMM: C = A @ B + bias (all fp32) ----------------
__global__ __launch_bounds__(256) void gemm_kernel(
    const float* __restrict__ A,
    const float* __restrict__ B,
    const float* __restrict__ bias,
    float* __restrict__ Cout,
    int M, int N, int K)
{
    __shared__ float As[64][33];
    __shared__ float Bs[32][65];
    const int t  = threadIdx.x;
    const int bm = blockIdx.x;
    const int bn = blockIdx.y;
    const int tx = t & 15;
    const int ty = t >> 4;

    float acc[4][4];
    #pragma unroll
    for (int r = 0; r < 4; ++r)
        #pragma unroll
        for (int c = 0; c < 4; ++c) acc[r][c] = 0.f;

    for (int k0 = 0; k0 < K; k0 += 32) {
        #pragma unroll
        for (int l = 0; l < 8; ++l) {
            int idx = t + l * 256;
            int row = idx >> 5, kk = idx & 31;
            As[row][kk] = A[(size_t)(bm * 64 + row) * K + k0 + kk];
        }
        #pragma unroll
        for (int l = 0; l < 8; ++l) {
            int idx = t + l * 256;
            int kr = idx >> 6, col = idx & 63;
            int gcol = bn * 64 + col;
            Bs[kr][col] = (gcol < N) ? B[(size_t)(k0 + kr) * N + gcol] : 0.f;
        }
        __syncthreads();
        #pragma unroll
        for (int kk = 0; kk < 32; ++kk) {
            float a[4], bb[4];
            #pragma unroll
            for (int r = 0; r < 4; ++r) a[r] = As[ty * 4 + r][kk];
            #pragma unroll
            for (int c = 0; c < 4; ++c) bb[c] = Bs[kk][tx * 4 + c];
            #pragma unroll
            for (int r = 0; r < 4; ++r)
                #pragma unroll
                for (int c = 0; c < 4; ++c) acc[r][c] += a[r] * bb[c];
        }
        __syncthreads();
    }

    #pragma unroll
    for (int r = 0; r < 4; ++r) {
        int row = bm * 64 + ty * 4 + r;
        #pragma unroll
        for (int c = 0; c < 4; ++c) {
            int col = bn * 64 + tx * 4 + c;
            if (col < N) {
                Cout[(size_t)row * N + col] = acc[r][c] + bias[col];
            }
        }
    }
}

// ---------------- Bias/gate table build ----------------
// Etab[br][h][i*128+k] = eg_br[r2*16 + h] + mask[r2]
// Gtab[br][h][i*128+k] = sigmoid(eg_br[r2*16 + 8 + h] + mask[r2])
// where r2 = i*128+k (br=0) or k*128+i (br=1).
__global__ __launch_bounds__(256) void tables_kernel(
    const float* __restrict__ eg_in, const float* __restrict__ eg_out,
    const float* __restrict__ mask,
    float* __restrict__ Etab, float* __restrict__ Gtab)
{
    int flat = blockIdx.x * 256 + threadIdx.x;   // 0..32767
    int br = flat >> 14;
    int p  = flat & 16383;                        // r2 = p (read-coalesced)
    const float* eg = br ? eg_out : eg_in;
    const float4* row = (const float4*)(eg + (size_t)p * 16);
    float4 r0 = row[0], r1 = row[1], r2 = row[2], r3 = row[3];
    float m = mask[p];
    float E[8] = {r0.x, r0.y, r0.z, r0.w, r1.x, r1.y, r1.z, r1.w};
    float G[8] = {r2.x, r2.y, r2.z, r2.w, r3.x, r3.y, r3.z, r3.w};
    int i, k;
    if (br == 0) { i = p >> 7; k = p & 127; }
    else         { k = p >> 7; i = p & 127; }
    int dst = i * 128 + k;
    #pragma unroll
    for (int h = 0; h < 8; ++h) {
        size_t off = (size_t)(br * 8 + h) * NPOS + dst;
        Etab[off] = E[h] + m;
        Gtab[off] = 1.f / (1.f + __expf(-(G[h] + m)));
    }
}

// ---------------- Fused triangle attention v2 ----------------
// grid (j=128, h=8, br=2), 256 threads. Thread owns rows i0,i0+1 and 32 k's:
// k = 16*kk + 4*(t&3) + cc. All softmax state in registers; quad shfl reduce.
__global__ __launch_bounds__(256) void attn_kernel(
    const float* __restrict__ qkv_in, const float* __restrict__ qkv_out,
    const float* __restrict__ Etab, const float* __restrict__ Gtab,
    float* __restrict__ va)
{
    const int j  = blockIdx.x;
    const int h  = blockIdx.y;
    const int br = blockIdx.z;
    const float* __restrict__ qkv = br ? qkv_out : qkv_in;
    const float* __restrict__ Eb = Etab + (size_t)(br * 8 + h) * NPOS;
    const float* __restrict__ Gb = Gtab + (size_t)(br * 8 + h) * NPOS;
    const int t = threadIdx.x;

    __shared__ float Qs[128][20];   // pad 20: 80B rows, 16B-aligned
    __shared__ float Ks[128][20];
    __shared__ float Vs[128][20];

    for (int idx = t; idx < 2048; idx += 256) {
        int r = idx >> 4, d = idx & 15;
        int qrow = r * 128 + j;
        int krow = br ? (r * 128 + j) : (j * 128 + r);
        Qs[r][d] = qkv[(size_t)qrow * 384 +       d * 8 + h] * 0.25f;
        Ks[r][d] = qkv[(size_t)krow * 384 + 128 + d * 8 + h];
        Vs[r][d] = qkv[(size_t)krow * 384 + 256 + d * 8 + h];
    }
    __syncthreads();

    const int c  = t & 3;      // k-quad lane
    const int i0 = (t >> 2) * 2;

    // Q rows -> registers
    float4 q0[4], q1[4];
    {
        const float4* Q0 = (const float4*)&Qs[i0][0];
        const float4* Q1 = (const float4*)&Qs[i0 + 1][0];
        #pragma unroll
        for (int x = 0; x < 4; ++x) { q0[x] = Q0[x]; q1[x] = Q1[x]; }
    }

    // init scores with bias (E) — loads issue early, overlap with QK below
    float s[2][32];
    #pragma unroll
    for (int kk = 0; kk < 8; ++kk) {
        float4 e0 = *(const float4*)&Eb[(size_t)i0 * 128 + 16 * kk + 4 * c];
        float4 e1 = *(const float4*)&Eb[(size_t)(i0 + 1) * 128 + 16 * kk + 4 * c];
        s[0][kk * 4 + 0] = e0.x; s[0][kk * 4 + 1] = e0.y;
        s[0][kk * 4 + 2] = e0.z; s[0][kk * 4 + 3] = e0.w;
        s[1][kk * 4 + 0] = e1.x; s[1][kk * 4 + 1] = e1.y;
        s[1][kk * 4 + 2] = e1.z; s[1][kk * 4 + 3] = e1.w;
    }

    // scores: S[i, k] += Q[i,:] . K[k,:]
    #pragma unroll
    for (int kk = 0; kk < 8; ++kk) {
        #pragma unroll
        for (int cc = 0; cc < 4; ++cc) {
            const int k = 16 * kk + 4 * c + cc;
            const float4* Kr = (const float4*)&Ks[k][0];
            float d0 = 0.f, d1 = 0.f;
            #pragma unroll
            for (int x = 0; x < 4; ++x) {
                float4 kv = Kr[x];
                d0 += q0[x].x * kv.x + q0[x].y * kv.y + q0[x].z * kv.z + q0[x].w * kv.w;
                d1 += q1[x].x * kv.x + q1[x].y * kv.y + q1[x].z * kv.z + q1[x].w * kv.w;
            }
            s[0][kk * 4 + cc] += d0;
            s[1][kk * 4 + cc] += d1;
        }
    }

    // softmax over k (32 own + quad butterfly)
    float mx0 = -1e30f, mx1 = -1e30f;
    #pragma unroll
    for (int x = 0; x < 32; ++x) { mx0 = fmaxf(mx0, s[0][x]); mx1 = fmaxf(mx1, s[1][x]); }
    mx0 = fmaxf(mx0, __shfl_xor(mx0, 1)); mx0 = fmaxf(mx0, __shfl_xor(mx0, 2));
    mx1 = fmaxf(mx1, __shfl_xor(mx1, 1)); mx1 = fmaxf(mx1, __shfl_xor(mx1, 2));
    float sm0 = 0.f, sm1 = 0.f;
    #pragma unroll
    for (int x = 0; x < 32; ++x) {
        float p0 = __expf(s[0][x] - mx0); s[0][x] = p0; sm0 += p0;
        float p1 = __expf(s[1][x] - mx1); s[1][x] = p1; sm1 += p1;
    }
    sm0 += __shfl_xor(sm0, 1); sm0 += __shfl_xor(sm0, 2);
    sm1 += __shfl_xor(sm1, 1); sm1 += __shfl_xor(sm1, 2);
    const float inv0 = 1.f / sm0, inv1 = 1.f / sm1;

    // apply gate * inv
    #pragma unroll
    for (int kk = 0; kk < 8; ++kk) {
        float4 g0 = *(const float4*)&Gb[(size_t)i0 * 128 + 16 * kk + 4 * c];
        float4 g1 = *(const float4*)&Gb[(size_t)(i0 + 1) * 128 + 16 * kk + 4 * c];
        s[0][kk * 4 + 0] *= inv0 * g0.x; s[0][kk * 4 + 1] *= inv0 * g0.y;
        s[0][kk * 4 + 2] *= inv0 * g0.z; s[0][kk * 4 + 3] *= inv0 * g0.w;
        s[1][kk * 4 + 0] *= inv1 * g1.x; s[1][kk * 4 + 1] *= inv1 * g1.y;
        s[1][kk * 4 + 2] *= inv1 * g1.z; s[1][kk * 4 + 3] *= inv1 * g1.w;
    }

    // Va[i, d] = sum_k A[i,k] * V[k, d]
    float acc0[16], acc1[16];
    #pragma unroll
    for (int d = 0; d < 16; ++d) { acc0[d] = 0.f; acc1[d] = 0.f; }
    #pragma unroll
    for (int kk = 0; kk < 8; ++kk) {
        #pragma unroll
        for (int cc = 0; cc < 4; ++cc) {
            const int k = 16 * kk + 4 * c + cc;
            const float4* Vr = (const float4*)&Vs[k][0];
            const float p0 = s[0][kk * 4 + cc];
            const float p1 = s[1][kk * 4 + cc];
            #pragma unroll
            for (int x = 0; x < 4; ++x) {
                float4 vv = Vr[x];
                acc0[x * 4 + 0] += p0 * vv.x; acc0[x * 4 + 1] += p0 * vv.y;
                acc0[x * 4 + 2] += p0 * vv.z; acc0[x * 4 + 3] += p0 * vv.w;
                acc1[x * 4 + 0] += p1 * vv.x; acc1[x * 4 + 1] += p1 * vv.y;
                acc1[x * 4 + 2] += p1 * vv.z; acc1[x * 4 + 3] += p1 * vv.w;
            }
        }
    }
    // quad reduce
    #pragma unroll
    for (int d = 0; d < 16; ++d) {
        acc0[d] += __shfl_xor(acc0[d], 1); acc0[d] += __shfl_xor(acc0[d], 2);
        acc1[d] += __shfl_xor(acc1[d], 1); acc1[d] += __shfl_xor(acc1[d], 2);
    }

    // lane c writes d in [4c, 4c+4) for both rows
    {
        size_t base0 = ((size_t)(i0 * 128 + j)) * 256 + br * 8 + h;
        size_t base1 = base0 + 128 * 256;
        #pragma unroll
        for (int x = 0; x < 4; ++x) {
            int d = 4 * c + x;
            va[base0 + (size_t)d * 16] = acc0[d];
            va[base1 + (size_t)d * 16] = acc1[d];
        }
    }
}

extern "C" void kernel_launch(void* const* d_in, const int* in_sizes, int n_in,
                              void* d_out, int out_size, void* d_ws, size_t ws_size,
                              hipStream_t stream) {
    const float* e        = (const float*)d_in[0];
    const float* mask     = (const float*)d_in[1];
    const float* ln_w     = (const float*)d_in[2];
    const float* ln_b     = (const float*)d_in[3];
    const float* w_qkv_in = (const float*)d_in[4];
    const float* b_qkv_in = (const float*)d_in[5];
    const float* w_eg_in  = (const float*)d_in[6];
    const float* b_eg_in  = (const float*)d_in[7];
    const float* w_qkv_o  = (const float*)d_in[8];
    const float* b_qkv_o  = (const float*)d_in[9];
    const float* w_eg_o   = (const float*)d_in[10];
    const float* b_eg_o   = (const float*)d_in[11];
    const float* w_o      = (const float*)d_in[12];
    const float* b_o      = (const float*)d_in[13];
    float* out = (float*)d_out;

    float* ws      = (float*)d_ws;
    float* e_ln    = ws;                               // 16384*128 (dead after GEMMs)
    float* qkv_i   = e_ln  + (size_t)NPOS * 128;       // 16384*384
    float* qkv_o   = qkv_i + (size_t)NPOS * 384;       // 16384*384
    float* eg_i    = qkv_o + (size_t)NPOS * 384;       // 16384*16
    float* eg_o    = eg_i  + (size_t)NPOS * 16;        // 16384*16
    float* va      = eg_o  + (size_t)NPOS * 16;        // 16384*256
    // tables alias the dead e_ln region (2 MB < 8 MB)
    float* Etab    = e_ln;                             // [2][8][16384]
    float* Gtab    = e_ln + (size_t)2 * 8 * NPOS;      // [2][8][16384]

    ln_kernel<<<NPOS, 128, 0, stream>>>(e, ln_w, ln_b, e_ln);

    gemm_kernel<<<dim3(NPOS / 64, 6), 256, 0, stream>>>(
        e_ln, w_qkv_in, b_qkv_in, qkv_i, NPOS, 384, 128);
    gemm_kernel<<<dim3(NPOS / 64, 6), 256, 0, stream>>>(
        e_ln, w_qkv_o, b_qkv_o, qkv_o, NPOS, 384, 128);
    gemm_kernel<<<dim3(NPOS / 64, 1), 256, 0, stream>>>(
        e_ln, w_eg_in, b_eg_in, eg_i, NPOS, 16, 128);
    gemm_kernel<<<dim3(NPOS / 64, 1), 256, 0, stream>>>(
        e_ln, w_eg_o, b_eg_o, eg_o, NPOS, 16, 128);

    tables_kernel<<<128, 256, 0, stream>>>(eg_i, eg_o, mask, Etab, Gtab);

    attn_kernel<<<dim3(128, 8, 2), 256, 0, stream>>>(
        qkv_i, qkv_o, Etab, Gtab, va);

    gemm_kernel<<<dim3(NPOS / 64, 2), 256, 0, stream>>>(
        va, w_o, b_o, out, NPOS, 128, 256);
}

// Round 4
// 268.696 us; speedup vs baseline: 2.1078x; 1.2104x over previous
//
#include <hip/hip_runtime.h>
#include <hip/hip_bf16.h>

// Problem: B=1, N=128, C=128, H=8, D=16. SCALE = 0.25. All I/O fp32.
// GEMMs via bf16 MFMA with split-bf16 (hi/lo) 3-term scheme for fp32-quality:
//   C = Ahi@Bhi + Alo@Bhi + Ahi@Blo   (missing Alo@Blo ~ 2^-18 relative)
// ws layout (bytes):
//   [0, 8.39M)   e_hl bf16 [16384][256] (hi cols 0-127, lo 128-255)
//                -- later aliased: Etab/Gtab at [0, 2.1M), B3t at [4.5M, 4.63M)
//   [8.39M, ...) qkv_i f32[16384][384], qkv_o, eg_i f32[16384][16], eg_o,
//                va f32[16384][256] (B1t/B2t packs alias va start, dead before attn)

#define NPOS 16384
#define CDIM 128

typedef __attribute__((ext_vector_type(8))) short bf16x8;
typedef __attribute__((ext_vector_type(4))) float f32x4;

static __device__ __forceinline__ unsigned short f2bf(float x) {
    union { float f; unsigned int u; } v; v.f = x;
    unsigned int u = v.u;
    unsigned int r = u + 0x7FFFu + ((u >> 16) & 1u);   // RNE
    return (unsigned short)(r >> 16);
}
static __device__ __forceinline__ float bf2f(unsigned short h) {
    union { float f; unsigned int u; } v; v.u = ((unsigned int)h) << 16; return v.f;
}

// ---------------- LayerNorm: e -> e_hl (bf16 hi|lo) ----------------
__global__ __launch_bounds__(128) void ln_kernel(
    const float* __restrict__ e,
    const float* __restrict__ w,
    const float* __restrict__ b,
    unsigned short* __restrict__ e_hl)
{
    const int row = blockIdx.x;
    const int t = threadIdx.x;
    float x = e[(size_t)row * CDIM + t];
    float s = x, s2 = x * x;
    #pragma unroll
    for (int off = 1; off < 64; off <<= 1) {
        s  += __shfl_xor(s,  off, 64);
        s2 += __shfl_xor(s2, off, 64);
    }
    __shared__ float sh[4];
    if ((t & 63) == 0) { sh[(t >> 6) * 2] = s; sh[(t >> 6) * 2 + 1] = s2; }
    __syncthreads();
    float sum = sh[0] + sh[2], sumsq = sh[1] + sh[3];
    float m = sum * (1.f / 128.f);
    float v = sumsq * (1.f / 128.f) - m * m;
    float sc = rsqrtf(v + 1e-5f);
    float y = (x - m) * sc * w[t] + b[t];
    unsigned short hi = f2bf(y);
    unsigned short lo = f2bf(y - bf2f(hi));
    e_hl[(size_t)row * 256 + t]       = hi;
    e_hl[(size_t)row * 256 + 128 + t] = lo;
}

// ---------------- Weight packs: fp32 [K][N] -> bf16 B^T [2][Npad][K] ----------------
// qkv+eg concat: n<384 from wq, 384<=n<400 from we, else 0. N=448, K=128. grid 224x256.
__global__ __launch_bounds__(256) void pack_qkv_w(
    const float* __restrict__ wq, const float* __restrict__ we,
    unsigned short* __restrict__ Bt)
{
    int idx = blockIdx.x * 256 + threadIdx.x;    // n*128 + k
    int n = idx >> 7, k = idx & 127;
    float v = 0.f;
    if (n < 384) v = wq[(size_t)k * 384 + n];
    else if (n < 400) v = we[(size_t)k * 16 + (n - 384)];
    unsigned short hi = f2bf(v);
    unsigned short lo = f2bf(v - bf2f(hi));
    Bt[idx] = hi;
    Bt[448 * 128 + idx] = lo;
}

// w_o: [256][128] -> [2][128][256]. grid 128x256.
__global__ __launch_bounds__(256) void pack_o_w(
    const float* __restrict__ wo, unsigned short* __restrict__ Bt)
{
    int idx = blockIdx.x * 256 + threadIdx.x;    // n*256 + k
    int n = idx >> 8, k = idx & 255;
    float v = wo[(size_t)k * 128 + n];
    unsigned short hi = f2bf(v);
    unsigned short lo = f2bf(v - bf2f(hi));
    Bt[idx] = hi;
    Bt[128 * 256 + idx] = lo;
}

// ---------------- MFMA GEMM: qkv (+eg rider), A prepacked hi|lo ----------------
// grid(128, 7), 256 thr = 4 waves. Block tile 128(M) x 64(N). K=128 (4 chunks).
__global__ __launch_bounds__(256) void gemm_qkv_kernel(
    const unsigned short* __restrict__ e_hl,   // [16384][256]
    const unsigned short* __restrict__ Bt,     // [2][448][128]
    const float* __restrict__ bias_qkv,        // [384]
    const float* __restrict__ bias_eg,         // [16]
    float* __restrict__ qkv,                   // [16384][384]
    float* __restrict__ eg)                    // [16384][16]
{
    const int t = threadIdx.x;
    const int wave = t >> 6, lane = t & 63;
    const int m = lane & 15, q = lane >> 4;
    const int W0 = blockIdx.x * 128 + wave * 32;
    const int N0 = blockIdx.y * 64;

    f32x4 acc[2][4];
    #pragma unroll
    for (int a = 0; a < 2; ++a)
        #pragma unroll
        for (int c = 0; c < 4; ++c) acc[a][c] = (f32x4){0.f, 0.f, 0.f, 0.f};

    const unsigned short* arow0 = e_hl + (size_t)(W0 + m) * 256;
    const unsigned short* arow1 = e_hl + (size_t)(W0 + 16 + m) * 256;
    const unsigned short* bcol[4];
    #pragma unroll
    for (int ns = 0; ns < 4; ++ns)
        bcol[ns] = Bt + (size_t)(N0 + ns * 16 + m) * 128;

    #pragma unroll
    for (int kc = 0; kc < 4; ++kc) {
        const int ko = kc * 32 + q * 8;
        bf16x8 a0h = *(const bf16x8*)(arow0 + ko);
        bf16x8 a0l = *(const bf16x8*)(arow0 + 128 + ko);
        bf16x8 a1h = *(const bf16x8*)(arow1 + ko);
        bf16x8 a1l = *(const bf16x8*)(arow1 + 128 + ko);
        #pragma unroll
        for (int ns = 0; ns < 4; ++ns) {
            bf16x8 bh = *(const bf16x8*)(bcol[ns] + ko);
            bf16x8 bl = *(const bf16x8*)(bcol[ns] + 448 * 128 + ko);
            acc[0][ns] = __builtin_amdgcn_mfma_f32_16x16x32_bf16(a0h, bh, acc[0][ns], 0, 0, 0);
            acc[1][ns] = __builtin_amdgcn_mfma_f32_16x16x32_bf16(a1h, bh, acc[1][ns], 0, 0, 0);
            acc[0][ns] = __builtin_amdgcn_mfma_f32_16x16x32_bf16(a0l, bh, acc[0][ns], 0, 0, 0);
            acc[1][ns] = __builtin_amdgcn_mfma_f32_16x16x32_bf16(a1l, bh, acc[1][ns], 0, 0, 0);
            acc[0][ns] = __builtin_amdgcn_mfma_f32_16x16x32_bf16(a0h, bl, acc[0][ns], 0, 0, 0);
            acc[1][ns] = __builtin_amdgcn_mfma_f32_16x16x32_bf16(a1h, bl, acc[1][ns], 0, 0, 0);
        }
    }

    #pragma unroll
    for (int ms = 0; ms < 2; ++ms) {
        #pragma unroll
        for (int ns = 0; ns < 4; ++ns) {
            int col = N0 + ns * 16 + m;
            #pragma unroll
            for (int r = 0; r < 4; ++r) {
                int row = W0 + ms * 16 + q * 4 + r;
                float v = acc[ms][ns][r];
                if (col < 384)
                    qkv[(size_t)row * 384 + col] = v + bias_qkv[col];
                else if (col < 400)
                    eg[(size_t)row * 16 + (col - 384)] = v + bias_eg[col - 384];
            }
        }
    }
}

// ---------------- MFMA GEMM: output, A = va fp32 split on the fly ----------------
// grid(128, 2). Block tile 128 x 64. K=256 (8 chunks).
__global__ __launch_bounds__(256) void gemm_out_kernel(
    const float* __restrict__ va,              // [16384][256]
    const unsigned short* __restrict__ B3t,    // [2][128][256]
    const float* __restrict__ bias,            // [128]
    float* __restrict__ out)                   // [16384][128]
{
    const int t = threadIdx.x;
    const int wave = t >> 6, lane = t & 63;
    const int m = lane & 15, q = lane >> 4;
    const int W0 = blockIdx.x * 128 + wave * 32;
    const int N0 = blockIdx.y * 64;

    f32x4 acc[2][4];
    #pragma unroll
    for (int a = 0; a < 2; ++a)
        #pragma unroll
        for (int c = 0; c < 4; ++c) acc[a][c] = (f32x4){0.f, 0.f, 0.f, 0.f};

    const float* arow[2] = { va + (size_t)(W0 + m) * 256,
                             va + (size_t)(W0 + 16 + m) * 256 };
    const unsigned short* bcol[4];
    #pragma unroll
    for (int ns = 0; ns < 4; ++ns)
        bcol[ns] = B3t + (size_t)(N0 + ns * 16 + m) * 256;

    #pragma unroll 2
    for (int kc = 0; kc < 8; ++kc) {
        const int ko = kc * 32 + q * 8;
        bf16x8 ah[2], al[2];
        #pragma unroll
        for (int ms = 0; ms < 2; ++ms) {
            const float4* ap = (const float4*)(arow[ms] + ko);
            float4 f0 = ap[0], f1 = ap[1];
            float xs[8] = {f0.x, f0.y, f0.z, f0.w, f1.x, f1.y, f1.z, f1.w};
            #pragma unroll
            for (int jj = 0; jj < 8; ++jj) {
                unsigned short h = f2bf(xs[jj]);
                ah[ms][jj] = (short)h;
                al[ms][jj] = (short)f2bf(xs[jj] - bf2f(h));
            }
        }
        #pragma unroll
        for (int ns = 0; ns < 4; ++ns) {
            bf16x8 bh = *(const bf16x8*)(bcol[ns] + ko);
            bf16x8 bl = *(const bf16x8*)(bcol[ns] + 128 * 256 + ko);
            acc[0][ns] = __builtin_amdgcn_mfma_f32_16x16x32_bf16(ah[0], bh, acc[0][ns], 0, 0, 0);
            acc[1][ns] = __builtin_amdgcn_mfma_f32_16x16x32_bf16(ah[1], bh, acc[1][ns], 0, 0, 0);
            acc[0][ns] = __builtin_amdgcn_mfma_f32_16x16x32_bf16(al[0], bh, acc[0][ns], 0, 0, 0);
            acc[1][ns] = __builtin_amdgcn_mfma_f32_16x16x32_bf16(al[1], bh, acc[1][ns], 0, 0, 0);
            acc[0][ns] = __builtin_amdgcn_mfma_f32_16x16x32_bf16(ah[0], bl, acc[0][ns], 0, 0, 0);
            acc[1][ns] = __builtin_amdgcn_mfma_f32_16x16x32_bf16(ah[1], bl, acc[1][ns], 0, 0, 0);
        }
    }

    #pragma unroll
    for (int ms = 0; ms < 2; ++ms) {
        #pragma unroll
        for (int ns = 0; ns < 4; ++ns) {
            int col = N0 + ns * 16 + m;
            #pragma unroll
            for (int r = 0; r < 4; ++r) {
                int row = W0 + ms * 16 + q * 4 + r;
                out[(size_t)row * 128 + col] = acc[ms][ns][r] + bias[col];
            }
        }
    }
}

// ---------------- Bias/gate tables ----------------
__global__ __launch_bounds__(256) void tables_kernel(
    const float* __restrict__ eg_in, const float* __restrict__ eg_out,
    const float* __restrict__ mask,
    float* __restrict__ Etab, float* __restrict__ Gtab)
{
    int flat = blockIdx.x * 256 + threadIdx.x;   // 0..32767
    int br = flat >> 14;
    int p  = flat & 16383;
    const float* eg = br ? eg_out : eg_in;
    const float4* row = (const float4*)(eg + (size_t)p * 16);
    float4 r0 = row[0], r1 = row[1], r2 = row[2], r3 = row[3];
    float m = mask[p];
    float E[8] = {r0.x, r0.y, r0.z, r0.w, r1.x, r1.y, r1.z, r1.w};
    float G[8] = {r2.x, r2.y, r2.z, r2.w, r3.x, r3.y, r3.z, r3.w};
    int i, k;
    if (br == 0) { i = p >> 7; k = p & 127; }
    else         { k = p >> 7; i = p & 127; }
    int dst = i * 128 + k;
    #pragma unroll
    for (int h = 0; h < 8; ++h) {
        size_t off = (size_t)(br * 8 + h) * NPOS + dst;
        Etab[off] = E[h] + m;
        Gtab[off] = 1.f / (1.f + __expf(-(G[h] + m)));
    }
}

// ---------------- Fused triangle attention (unchanged from round 3) ----------------
__global__ __launch_bounds__(256) void attn_kernel(
    const float* __restrict__ qkv_in, const float* __restrict__ qkv_out,
    const float* __restrict__ Etab, const float* __restrict__ Gtab,
    float* __restrict__ va)
{
    const int j  = blockIdx.x;
    const int h  = blockIdx.y;
    const int br = blockIdx.z;
    const float* __restrict__ qkv = br ? qkv_out : qkv_in;
    const float* __restrict__ Eb = Etab + (size_t)(br * 8 + h) * NPOS;
    const float* __restrict__ Gb = Gtab + (size_t)(br * 8 + h) * NPOS;
    const int t = threadIdx.x;

    __shared__ float Qs[128][20];
    __shared__ float Ks[128][20];
    __shared__ float Vs[128][20];

    for (int idx = t; idx < 2048; idx += 256) {
        int r = idx >> 4, d = idx & 15;
        int qrow = r * 128 + j;
        int krow = br ? (r * 128 + j) : (j * 128 + r);
        Qs[r][d] = qkv[(size_t)qrow * 384 +       d * 8 + h] * 0.25f;
        Ks[r][d] = qkv[(size_t)krow * 384 + 128 + d * 8 + h];
        Vs[r][d] = qkv[(size_t)krow * 384 + 256 + d * 8 + h];
    }
    __syncthreads();

    const int c  = t & 3;
    const int i0 = (t >> 2) * 2;

    float4 q0[4], q1[4];
    {
        const float4* Q0 = (const float4*)&Qs[i0][0];
        const float4* Q1 = (const float4*)&Qs[i0 + 1][0];
        #pragma unroll
        for (int x = 0; x < 4; ++x) { q0[x] = Q0[x]; q1[x] = Q1[x]; }
    }

    float s[2][32];
    #pragma unroll
    for (int kk = 0; kk < 8; ++kk) {
        float4 e0 = *(const float4*)&Eb[(size_t)i0 * 128 + 16 * kk + 4 * c];
        float4 e1 = *(const float4*)&Eb[(size_t)(i0 + 1) * 128 + 16 * kk + 4 * c];
        s[0][kk * 4 + 0] = e0.x; s[0][kk * 4 + 1] = e0.y;
        s[0][kk * 4 + 2] = e0.z; s[0][kk * 4 + 3] = e0.w;
        s[1][kk * 4 + 0] = e1.x; s[1][kk * 4 + 1] = e1.y;
        s[1][kk * 4 + 2] = e1.z; s[1][kk * 4 + 3] = e1.w;
    }

    #pragma unroll
    for (int kk = 0; kk < 8; ++kk) {
        #pragma unroll
        for (int cc = 0; cc < 4; ++cc) {
            const int k = 16 * kk + 4 * c + cc;
            const float4* Kr = (const float4*)&Ks[k][0];
            float d0 = 0.f, d1 = 0.f;
            #pragma unroll
            for (int x = 0; x < 4; ++x) {
                float4 kv = Kr[x];
                d0 += q0[x].x * kv.x + q0[x].y * kv.y + q0[x].z * kv.z + q0[x].w * kv.w;
                d1 += q1[x].x * kv.x + q1[x].y * kv.y + q1[x].z * kv.z + q1[x].w * kv.w;
            }
            s[0][kk * 4 + cc] += d0;
            s[1][kk * 4 + cc] += d1;
        }
    }

    float mx0 = -1e30f, mx1 = -1e30f;
    #pragma unroll
    for (int x = 0; x < 32; ++x) { mx0 = fmaxf(mx0, s[0][x]); mx1 = fmaxf(mx1, s[1][x]); }
    mx0 = fmaxf(mx0, __shfl_xor(mx0, 1)); mx0 = fmaxf(mx0, __shfl_xor(mx0, 2));
    mx1 = fmaxf(mx1, __shfl_xor(mx1, 1)); mx1 = fmaxf(mx1, __shfl_xor(mx1, 2));
    float sm0 = 0.f, sm1 = 0.f;
    #pragma unroll
    for (int x = 0; x < 32; ++x) {
        float p0 = __expf(s[0][x] - mx0); s[0][x] = p0; sm0 += p0;
        float p1 = __expf(s[1][x] - mx1); s[1][x] = p1; sm1 += p1;
    }
    sm0 += __shfl_xor(sm0, 1); sm0 += __shfl_xor(sm0, 2);
    sm1 += __shfl_xor(sm1, 1); sm1 += __shfl_xor(sm1, 2);
    const float inv0 = 1.f / sm0, inv1 = 1.f / sm1;

    #pragma unroll
    for (int kk = 0; kk < 8; ++kk) {
        float4 g0 = *(const float4*)&Gb[(size_t)i0 * 128 + 16 * kk + 4 * c];
        float4 g1 = *(const float4*)&Gb[(size_t)(i0 + 1) * 128 + 16 * kk + 4 * c];
        s[0][kk * 4 + 0] *= inv0 * g0.x; s[0][kk * 4 + 1] *= inv0 * g0.y;
        s[0][kk * 4 + 2] *= inv0 * g0.z; s[0][kk * 4 + 3] *= inv0 * g0.w;
        s[1][kk * 4 + 0] *= inv1 * g1.x; s[1][kk * 4 + 1] *= inv1 * g1.y;
        s[1][kk * 4 + 2] *= inv1 * g1.z; s[1][kk * 4 + 3] *= inv1 * g1.w;
    }

    float acc0[16], acc1[16];
    #pragma unroll
    for (int d = 0; d < 16; ++d) { acc0[d] = 0.f; acc1[d] = 0.f; }
    #pragma unroll
    for (int kk = 0; kk < 8; ++kk) {
        #pragma unroll
        for (int cc = 0; cc < 4; ++cc) {
            const int k = 16 * kk + 4 * c + cc;
            const float4* Vr = (const float4*)&Vs[k][0];
            const float p0 = s[0][kk * 4 + cc];
            const float p1 = s[1][kk * 4 + cc];
            #pragma unroll
            for (int x = 0; x < 4; ++x) {
                float4 vv = Vr[x];
                acc0[x * 4 + 0] += p0 * vv.x; acc0[x * 4 + 1] += p0 * vv.y;
                acc0[x * 4 + 2] += p0 * vv.z; acc0[x * 4 + 3] += p0 * vv.w;
                acc1[x * 4 + 0] += p1 * vv.x; acc1[x * 4 + 1] += p1 * vv.y;
                acc1[x * 4 + 2] += p1 * vv.z; acc1[x * 4 + 3] += p1 * vv.w;
            }
        }
    }
    #pragma unroll
    for (int d = 0; d < 16; ++d) {
        acc0[d] += __shfl_xor(acc0[d], 1); acc0[d] += __shfl_xor(acc0[d], 2);
        acc1[d] += __shfl_xor(acc1[d], 1); acc1[d] += __shfl_xor(acc1[d], 2);
    }

    {
        size_t base0 = ((size_t)(i0 * 128 + j)) * 256 + br * 8 + h;
        size_t base1 = base0 + 128 * 256;
        #pragma unroll
        for (int x = 0; x < 4; ++x) {
            int d = 4 * c + x;
            va[base0 + (size_t)d * 16] = acc0[d];
            va[base1 + (size_t)d * 16] = acc1[d];
        }
    }
}

extern "C" void kernel_launch(void* const* d_in, const int* in_sizes, int n_in,
                              void* d_out, int out_size, void* d_ws, size_t ws_size,
                              hipStream_t stream) {
    const float* e        = (const float*)d_in[0];
    const float* mask     = (const float*)d_in[1];
    const float* ln_w     = (const float*)d_in[2];
    const float* ln_b     = (const float*)d_in[3];
    const float* w_qkv_in = (const float*)d_in[4];
    const float* b_qkv_in = (const float*)d_in[5];
    const float* w_eg_in  = (const float*)d_in[6];
    const float* b_eg_in  = (const float*)d_in[7];
    const float* w_qkv_o  = (const float*)d_in[8];
    const float* b_qkv_o  = (const float*)d_in[9];
    const float* w_eg_o   = (const float*)d_in[10];
    const float* b_eg_o   = (const float*)d_in[11];
    const float* w_o      = (const float*)d_in[12];
    const float* b_o      = (const float*)d_in[13];
    float* out = (float*)d_out;

    char* base = (char*)d_ws;
    unsigned short* e_hl = (unsigned short*)base;                    // 8.39 MB
    float* qkv_i = (float*)(base + (size_t)NPOS * 256 * 2);          // 16384*384 f32
    float* qkv_o = qkv_i + (size_t)NPOS * 384;
    float* eg_i  = qkv_o + (size_t)NPOS * 384;
    float* eg_o  = eg_i  + (size_t)NPOS * 16;
    float* va    = eg_o  + (size_t)NPOS * 16;                        // 16384*256 f32

    // aliases (lifetime-checked):
    float* Etab = (float*)base;                                      // after e_hl dead
    float* Gtab = Etab + (size_t)2 * 8 * NPOS;
    unsigned short* B3t = (unsigned short*)(base + 4 * 1024 * 1024 + 512 * 1024);
    unsigned short* B1t = (unsigned short*)va;                       // dead before attn writes va
    unsigned short* B2t = B1t + (size_t)2 * 448 * 128;

    ln_kernel<<<NPOS, 128, 0, stream>>>(e, ln_w, ln_b, e_hl);

    pack_qkv_w<<<224, 256, 0, stream>>>(w_qkv_in, w_eg_in, B1t);
    pack_qkv_w<<<224, 256, 0, stream>>>(w_qkv_o,  w_eg_o,  B2t);

    gemm_qkv_kernel<<<dim3(128, 7), 256, 0, stream>>>(
        e_hl, B1t, b_qkv_in, b_eg_in, qkv_i, eg_i);
    gemm_qkv_kernel<<<dim3(128, 7), 256, 0, stream>>>(
        e_hl, B2t, b_qkv_o, b_eg_o, qkv_o, eg_o);

    pack_o_w<<<128, 256, 0, stream>>>(w_o, B3t);   // e_hl region dead now

    tables_kernel<<<128, 256, 0, stream>>>(eg_i, eg_o, mask, Etab, Gtab);

    attn_kernel<<<dim3(128, 8, 2), 256, 0, stream>>>(
        qkv_i, qkv_o, Etab, Gtab, va);

    gemm_out_kernel<<<dim3(128, 2), 256, 0, stream>>>(va, B3t, b_o, out);
}

// Round 5
// 258.765 us; speedup vs baseline: 2.1887x; 1.0384x over previous
//
#include <hip/hip_runtime.h>
#include <hip/hip_bf16.h>

// B=1, N=128, C=128, H=8, D=16. SCALE=0.25. All I/O fp32.
// GEMMs: bf16 MFMA, split-bf16 3-term (C = Ah@Bh + Al@Bh + Ah@Bl).
// qkv GEMM writes Q/K/V directly as per-(br,h) planes [br][h][p][16] f32,
// scale folded into Q. attn reads planes with coalesced float4s.
// ws (74.7 MB):
//   [0, 8.39M)  e_hl ushort[16384][256]   (aliased after use: Etab 1M, Gtab 1M, B3t)
//   [8.39M)     Qp f32[2][8][16384][16] (16M), Kp (16M), Vp (16M)
//   [56.7M)     eg_i f32[16384][16] (1M), eg_o (1M)
//   [58.7M)     va f32[16384][256] (16M)   (B1t/B2t alias start, dead before attn)

#define NPOS 16384
#define CDIM 128

typedef __attribute__((ext_vector_type(8))) short bf16x8;
typedef __attribute__((ext_vector_type(4))) float f32x4;

static __device__ __forceinline__ unsigned short f2bf(float x) {
    union { float f; unsigned int u; } v; v.f = x;
    unsigned int u = v.u;
    unsigned int r = u + 0x7FFFu + ((u >> 16) & 1u);   // RNE
    return (unsigned short)(r >> 16);
}
static __device__ __forceinline__ float bf2f(unsigned short h) {
    union { float f; unsigned int u; } v; v.u = ((unsigned int)h) << 16; return v.f;
}

// ---------------- LayerNorm: wave-per-row, no LDS ----------------
__global__ __launch_bounds__(256) void ln_kernel(
    const float* __restrict__ e,
    const float* __restrict__ w,
    const float* __restrict__ b,
    unsigned short* __restrict__ e_hl)
{
    const int t = threadIdx.x;
    const int lane = t & 63;
    const int row = blockIdx.x * 4 + (t >> 6);
    float2 x = *(const float2*)(e + (size_t)row * CDIM + lane * 2);
    float s = x.x + x.y, s2 = x.x * x.x + x.y * x.y;
    #pragma unroll
    for (int off = 1; off < 64; off <<= 1) {
        s  += __shfl_xor(s,  off, 64);
        s2 += __shfl_xor(s2, off, 64);
    }
    float m = s * (1.f / 128.f);
    float v = s2 * (1.f / 128.f) - m * m;
    float sc = rsqrtf(v + 1e-5f);
    float2 wv = *(const float2*)(w + lane * 2);
    float2 bv = *(const float2*)(b + lane * 2);
    float y0 = (x.x - m) * sc * wv.x + bv.x;
    float y1 = (x.y - m) * sc * wv.y + bv.y;
    unsigned short h0 = f2bf(y0), h1 = f2bf(y1);
    ushort2 hi = {h0, h1};
    ushort2 lo = {f2bf(y0 - bf2f(h0)), f2bf(y1 - bf2f(h1))};
    *(ushort2*)(e_hl + (size_t)row * 256 + lane * 2)       = hi;
    *(ushort2*)(e_hl + (size_t)row * 256 + 128 + lane * 2) = lo;
}

// ---------------- Weight packs ----------------
__global__ __launch_bounds__(256) void pack_qkv_w(
    const float* __restrict__ wq, const float* __restrict__ we,
    unsigned short* __restrict__ Bt)
{
    int idx = blockIdx.x * 256 + threadIdx.x;    // n*128 + k
    int n = idx >> 7, k = idx & 127;
    float v = 0.f;
    if (n < 384) v = wq[(size_t)k * 384 + n];
    else if (n < 400) v = we[(size_t)k * 16 + (n - 384)];
    unsigned short hi = f2bf(v);
    Bt[idx] = hi;
    Bt[448 * 128 + idx] = f2bf(v - bf2f(hi));
}

__global__ __launch_bounds__(256) void pack_o_w(
    const float* __restrict__ wo, unsigned short* __restrict__ Bt)
{
    int idx = blockIdx.x * 256 + threadIdx.x;    // n*256 + k
    int n = idx >> 8, k = idx & 255;
    float v = wo[(size_t)k * 128 + n];
    unsigned short hi = f2bf(v);
    Bt[idx] = hi;
    Bt[128 * 256 + idx] = f2bf(v - bf2f(hi));
}

// ---------------- MFMA GEMM: qkv+eg, writes per-(br,h) planes ----------------
// grid(128, 7, 2), 256 thr. Tile 128(M) x 64(N). K=128.
__global__ __launch_bounds__(256) void gemm_qkv_kernel(
    const unsigned short* __restrict__ e_hl,
    const unsigned short* __restrict__ B1t, const unsigned short* __restrict__ B2t,
    const float* __restrict__ bq_i, const float* __restrict__ be_i,
    const float* __restrict__ bq_o, const float* __restrict__ be_o,
    float* __restrict__ Qp, float* __restrict__ Kp, float* __restrict__ Vp,
    float* __restrict__ eg_i, float* __restrict__ eg_o)
{
    const int t = threadIdx.x;
    const int wave = t >> 6, lane = t & 63;
    const int m = lane & 15, q = lane >> 4;
    const int W0 = blockIdx.x * 128 + wave * 32;
    const int N0 = blockIdx.y * 64;
    const int br = blockIdx.z;
    const unsigned short* Bt = br ? B2t : B1t;
    const float* bias_qkv = br ? bq_o : bq_i;
    const float* bias_eg  = br ? be_o : be_i;
    float* eg = br ? eg_o : eg_i;

    f32x4 acc[2][4];
    #pragma unroll
    for (int a = 0; a < 2; ++a)
        #pragma unroll
        for (int c = 0; c < 4; ++c) acc[a][c] = (f32x4){0.f, 0.f, 0.f, 0.f};

    const unsigned short* arow0 = e_hl + (size_t)(W0 + m) * 256;
    const unsigned short* arow1 = e_hl + (size_t)(W0 + 16 + m) * 256;
    const unsigned short* bcol[4];
    #pragma unroll
    for (int ns = 0; ns < 4; ++ns)
        bcol[ns] = Bt + (size_t)(N0 + ns * 16 + m) * 128;

    #pragma unroll
    for (int kc = 0; kc < 4; ++kc) {
        const int ko = kc * 32 + q * 8;
        bf16x8 a0h = *(const bf16x8*)(arow0 + ko);
        bf16x8 a0l = *(const bf16x8*)(arow0 + 128 + ko);
        bf16x8 a1h = *(const bf16x8*)(arow1 + ko);
        bf16x8 a1l = *(const bf16x8*)(arow1 + 128 + ko);
        bf16x8 bh[4], bl[4];
        #pragma unroll
        for (int ns = 0; ns < 4; ++ns) {
            bh[ns] = *(const bf16x8*)(bcol[ns] + ko);
            bl[ns] = *(const bf16x8*)(bcol[ns] + 448 * 128 + ko);
        }
        #pragma unroll
        for (int ns = 0; ns < 4; ++ns) {
            acc[0][ns] = __builtin_amdgcn_mfma_f32_16x16x32_bf16(a0h, bh[ns], acc[0][ns], 0, 0, 0);
            acc[1][ns] = __builtin_amdgcn_mfma_f32_16x16x32_bf16(a1h, bh[ns], acc[1][ns], 0, 0, 0);
        }
        #pragma unroll
        for (int ns = 0; ns < 4; ++ns) {
            acc[0][ns] = __builtin_amdgcn_mfma_f32_16x16x32_bf16(a0l, bh[ns], acc[0][ns], 0, 0, 0);
            acc[1][ns] = __builtin_amdgcn_mfma_f32_16x16x32_bf16(a1l, bh[ns], acc[1][ns], 0, 0, 0);
        }
        #pragma unroll
        for (int ns = 0; ns < 4; ++ns) {
            acc[0][ns] = __builtin_amdgcn_mfma_f32_16x16x32_bf16(a0h, bl[ns], acc[0][ns], 0, 0, 0);
            acc[1][ns] = __builtin_amdgcn_mfma_f32_16x16x32_bf16(a1h, bl[ns], acc[1][ns], 0, 0, 0);
        }
    }

    #pragma unroll
    for (int ms = 0; ms < 2; ++ms) {
        #pragma unroll
        for (int ns = 0; ns < 4; ++ns) {
            const int col = N0 + ns * 16 + m;
            #pragma unroll
            for (int r = 0; r < 4; ++r) {
                const int row = W0 + ms * 16 + q * 4 + r;
                float v = acc[ms][ns][r];
                if (col < 128) {
                    int hh = col & 7, d = col >> 3;
                    Qp[((size_t)(br * 8 + hh) * NPOS + row) * 16 + d] =
                        (v + bias_qkv[col]) * 0.25f;
                } else if (col < 256) {
                    int c2 = col - 128, hh = c2 & 7, d = c2 >> 3;
                    Kp[((size_t)(br * 8 + hh) * NPOS + row) * 16 + d] = v + bias_qkv[col];
                } else if (col < 384) {
                    int c2 = col - 256, hh = c2 & 7, d = c2 >> 3;
                    Vp[((size_t)(br * 8 + hh) * NPOS + row) * 16 + d] = v + bias_qkv[col];
                } else if (col < 400) {
                    eg[(size_t)row * 16 + (col - 384)] = v + bias_eg[col - 384];
                }
            }
        }
    }
}

// ---------------- MFMA GEMM: output projection ----------------
// grid(256, 2), 256 thr. Tile 64(M) x 64(N), wave owns 16 rows. K=256.
__global__ __launch_bounds__(256) void gemm_out_kernel(
    const float* __restrict__ va,
    const unsigned short* __restrict__ B3t,
    const float* __restrict__ bias,
    float* __restrict__ out)
{
    const int t = threadIdx.x;
    const int wave = t >> 6, lane = t & 63;
    const int m = lane & 15, q = lane >> 4;
    const int W0 = blockIdx.x * 64 + wave * 16;
    const int N0 = blockIdx.y * 64;

    f32x4 acc[4];
    #pragma unroll
    for (int c = 0; c < 4; ++c) acc[c] = (f32x4){0.f, 0.f, 0.f, 0.f};

    const float* arow = va + (size_t)(W0 + m) * 256;
    const unsigned short* bcol[4];
    #pragma unroll
    for (int ns = 0; ns < 4; ++ns)
        bcol[ns] = B3t + (size_t)(N0 + ns * 16 + m) * 256;

    #pragma unroll 2
    for (int kc = 0; kc < 8; ++kc) {
        const int ko = kc * 32 + q * 8;
        const float4* ap = (const float4*)(arow + ko);
        float4 f0 = ap[0], f1 = ap[1];
        float xs[8] = {f0.x, f0.y, f0.z, f0.w, f1.x, f1.y, f1.z, f1.w};
        bf16x8 ah, al;
        #pragma unroll
        for (int jj = 0; jj < 8; ++jj) {
            unsigned short h = f2bf(xs[jj]);
            ah[jj] = (short)h;
            al[jj] = (short)f2bf(xs[jj] - bf2f(h));
        }
        bf16x8 bh[4], bl[4];
        #pragma unroll
        for (int ns = 0; ns < 4; ++ns) {
            bh[ns] = *(const bf16x8*)(bcol[ns] + ko);
            bl[ns] = *(const bf16x8*)(bcol[ns] + 128 * 256 + ko);
        }
        #pragma unroll
        for (int ns = 0; ns < 4; ++ns)
            acc[ns] = __builtin_amdgcn_mfma_f32_16x16x32_bf16(ah, bh[ns], acc[ns], 0, 0, 0);
        #pragma unroll
        for (int ns = 0; ns < 4; ++ns)
            acc[ns] = __builtin_amdgcn_mfma_f32_16x16x32_bf16(al, bh[ns], acc[ns], 0, 0, 0);
        #pragma unroll
        for (int ns = 0; ns < 4; ++ns)
            acc[ns] = __builtin_amdgcn_mfma_f32_16x16x32_bf16(ah, bl[ns], acc[ns], 0, 0, 0);
    }

    #pragma unroll
    for (int ns = 0; ns < 4; ++ns) {
        const int col = N0 + ns * 16 + m;
        #pragma unroll
        for (int r = 0; r < 4; ++r) {
            const int row = W0 + q * 4 + r;
            out[(size_t)row * 128 + col] = acc[ns][r] + bias[col];
        }
    }
}

// ---------------- Bias/gate tables ----------------
__global__ __launch_bounds__(256) void tables_kernel(
    const float* __restrict__ eg_in, const float* __restrict__ eg_out,
    const float* __restrict__ mask,
    float* __restrict__ Etab, float* __restrict__ Gtab)
{
    int flat = blockIdx.x * 256 + threadIdx.x;   // 0..32767
    int br = flat >> 14;
    int p  = flat & 16383;
    const float* eg = br ? eg_out : eg_in;
    const float4* row = (const float4*)(eg + (size_t)p * 16);
    float4 r0 = row[0], r1 = row[1], r2 = row[2], r3 = row[3];
    float m = mask[p];
    float E[8] = {r0.x, r0.y, r0.z, r0.w, r1.x, r1.y, r1.z, r1.w};
    float G[8] = {r2.x, r2.y, r2.z, r2.w, r3.x, r3.y, r3.z, r3.w};
    int i, k;
    if (br == 0) { i = p >> 7; k = p & 127; }
    else         { k = p >> 7; i = p & 127; }
    int dst = i * 128 + k;
    #pragma unroll
    for (int h = 0; h < 8; ++h) {
        size_t off = (size_t)(br * 8 + h) * NPOS + dst;
        Etab[off] = E[h] + m;
        Gtab[off] = 1.f / (1.f + __expf(-(G[h] + m)));
    }
}

// ---------------- Fused triangle attention v3 ----------------
// grid (j=128, h=8, br=2), 256 thr. K/V in LDS (coalesced float4 staging),
// Q direct to registers from Qp plane. Math identical to v2.
__global__ __launch_bounds__(256) void attn_kernel(
    const float* __restrict__ Qp, const float* __restrict__ Kp,
    const float* __restrict__ Vp,
    const float* __restrict__ Etab, const float* __restrict__ Gtab,
    float* __restrict__ va)
{
    const int j  = blockIdx.x;
    const int h  = blockIdx.y;
    const int br = blockIdx.z;
    const int t = threadIdx.x;
    const size_t plane = (size_t)(br * 8 + h) * NPOS;
    const float* __restrict__ Qpl = Qp + plane * 16;
    const float* __restrict__ Kpl = Kp + plane * 16;
    const float* __restrict__ Vpl = Vp + plane * 16;
    const float* __restrict__ Eb = Etab + plane;
    const float* __restrict__ Gb = Gtab + plane;

    __shared__ float Ks[128][20];
    __shared__ float Vs[128][20];

    #pragma unroll
    for (int it = 0; it < 2; ++it) {
        int v = t + it * 256;            // 0..511
        int k = v >> 2, dq = (v & 3) * 4;
        size_t p = br ? ((size_t)k * 128 + j) : ((size_t)j * 128 + k);
        float4 kv = *(const float4*)(Kpl + p * 16 + dq);
        float4 vv = *(const float4*)(Vpl + p * 16 + dq);
        *(float4*)&Ks[k][dq] = kv;
        *(float4*)&Vs[k][dq] = vv;
    }
    __syncthreads();

    const int c  = t & 3;
    const int i0 = (t >> 2) * 2;

    float4 q0[4], q1[4];
    {
        const float4* Q0 = (const float4*)(Qpl + (size_t)(i0 * 128 + j) * 16);
        const float4* Q1 = (const float4*)(Qpl + (size_t)((i0 + 1) * 128 + j) * 16);
        #pragma unroll
        for (int x = 0; x < 4; ++x) { q0[x] = Q0[x]; q1[x] = Q1[x]; }
    }

    float s[2][32];
    #pragma unroll
    for (int kk = 0; kk < 8; ++kk) {
        float4 e0 = *(const float4*)&Eb[(size_t)i0 * 128 + 16 * kk + 4 * c];
        float4 e1 = *(const float4*)&Eb[(size_t)(i0 + 1) * 128 + 16 * kk + 4 * c];
        s[0][kk * 4 + 0] = e0.x; s[0][kk * 4 + 1] = e0.y;
        s[0][kk * 4 + 2] = e0.z; s[0][kk * 4 + 3] = e0.w;
        s[1][kk * 4 + 0] = e1.x; s[1][kk * 4 + 1] = e1.y;
        s[1][kk * 4 + 2] = e1.z; s[1][kk * 4 + 3] = e1.w;
    }

    #pragma unroll
    for (int kk = 0; kk < 8; ++kk) {
        #pragma unroll
        for (int cc = 0; cc < 4; ++cc) {
            const int k = 16 * kk + 4 * c + cc;
            const float4* Kr = (const float4*)&Ks[k][0];
            float d0 = 0.f, d1 = 0.f;
            #pragma unroll
            for (int x = 0; x < 4; ++x) {
                float4 kv = Kr[x];
                d0 += q0[x].x * kv.x + q0[x].y * kv.y + q0[x].z * kv.z + q0[x].w * kv.w;
                d1 += q1[x].x * kv.x + q1[x].y * kv.y + q1[x].z * kv.z + q1[x].w * kv.w;
            }
            s[0][kk * 4 + cc] += d0;
            s[1][kk * 4 + cc] += d1;
        }
    }

    float mx0 = -1e30f, mx1 = -1e30f;
    #pragma unroll
    for (int x = 0; x < 32; ++x) { mx0 = fmaxf(mx0, s[0][x]); mx1 = fmaxf(mx1, s[1][x]); }
    mx0 = fmaxf(mx0, __shfl_xor(mx0, 1)); mx0 = fmaxf(mx0, __shfl_xor(mx0, 2));
    mx1 = fmaxf(mx1, __shfl_xor(mx1, 1)); mx1 = fmaxf(mx1, __shfl_xor(mx1, 2));
    float sm0 = 0.f, sm1 = 0.f;
    #pragma unroll
    for (int x = 0; x < 32; ++x) {
        float p0 = __expf(s[0][x] - mx0); s[0][x] = p0; sm0 += p0;
        float p1 = __expf(s[1][x] - mx1); s[1][x] = p1; sm1 += p1;
    }
    sm0 += __shfl_xor(sm0, 1); sm0 += __shfl_xor(sm0, 2);
    sm1 += __shfl_xor(sm1, 1); sm1 += __shfl_xor(sm1, 2);
    const float inv0 = 1.f / sm0, inv1 = 1.f / sm1;

    #pragma unroll
    for (int kk = 0; kk < 8; ++kk) {
        float4 g0 = *(const float4*)&Gb[(size_t)i0 * 128 + 16 * kk + 4 * c];
        float4 g1 = *(const float4*)&Gb[(size_t)(i0 + 1) * 128 + 16 * kk + 4 * c];
        s[0][kk * 4 + 0] *= inv0 * g0.x; s[0][kk * 4 + 1] *= inv0 * g0.y;
        s[0][kk * 4 + 2] *= inv0 * g0.z; s[0][kk * 4 + 3] *= inv0 * g0.w;
        s[1][kk * 4 + 0] *= inv1 * g1.x; s[1][kk * 4 + 1] *= inv1 * g1.y;
        s[1][kk * 4 + 2] *= inv1 * g1.z; s[1][kk * 4 + 3] *= inv1 * g1.w;
    }

    float acc0[16], acc1[16];
    #pragma unroll
    for (int d = 0; d < 16; ++d) { acc0[d] = 0.f; acc1[d] = 0.f; }
    #pragma unroll
    for (int kk = 0; kk < 8; ++kk) {
        #pragma unroll
        for (int cc = 0; cc < 4; ++cc) {
            const int k = 16 * kk + 4 * c + cc;
            const float4* Vr = (const float4*)&Vs[k][0];
            const float p0 = s[0][kk * 4 + cc];
            const float p1 = s[1][kk * 4 + cc];
            #pragma unroll
            for (int x = 0; x < 4; ++x) {
                float4 vv = Vr[x];
                acc0[x * 4 + 0] += p0 * vv.x; acc0[x * 4 + 1] += p0 * vv.y;
                acc0[x * 4 + 2] += p0 * vv.z; acc0[x * 4 + 3] += p0 * vv.w;
                acc1[x * 4 + 0] += p1 * vv.x; acc1[x * 4 + 1] += p1 * vv.y;
                acc1[x * 4 + 2] += p1 * vv.z; acc1[x * 4 + 3] += p1 * vv.w;
            }
        }
    }
    #pragma unroll
    for (int d = 0; d < 16; ++d) {
        acc0[d] += __shfl_xor(acc0[d], 1); acc0[d] += __shfl_xor(acc0[d], 2);
        acc1[d] += __shfl_xor(acc1[d], 1); acc1[d] += __shfl_xor(acc1[d], 2);
    }

    {
        size_t base0 = ((size_t)(i0 * 128 + j)) * 256 + br * 8 + h;
        size_t base1 = base0 + 128 * 256;
        #pragma unroll
        for (int x = 0; x < 4; ++x) {
            int d = 4 * c + x;
            va[base0 + (size_t)d * 16] = acc0[d];
            va[base1 + (size_t)d * 16] = acc1[d];
        }
    }
}

extern "C" void kernel_launch(void* const* d_in, const int* in_sizes, int n_in,
                              void* d_out, int out_size, void* d_ws, size_t ws_size,
                              hipStream_t stream) {
    const float* e        = (const float*)d_in[0];
    const float* mask     = (const float*)d_in[1];
    const float* ln_w     = (const float*)d_in[2];
    const float* ln_b     = (const float*)d_in[3];
    const float* w_qkv_in = (const float*)d_in[4];
    const float* b_qkv_in = (const float*)d_in[5];
    const float* w_eg_in  = (const float*)d_in[6];
    const float* b_eg_in  = (const float*)d_in[7];
    const float* w_qkv_o  = (const float*)d_in[8];
    const float* b_qkv_o  = (const float*)d_in[9];
    const float* w_eg_o   = (const float*)d_in[10];
    const float* b_eg_o   = (const float*)d_in[11];
    const float* w_o      = (const float*)d_in[12];
    const float* b_o      = (const float*)d_in[13];
    float* out = (float*)d_out;

    char* base = (char*)d_ws;
    unsigned short* e_hl = (unsigned short*)base;                         // 8.39 MB
    float* Qp   = (float*)(base + (size_t)NPOS * 256 * 2);                // 16 MB
    float* Kp   = Qp + (size_t)16 * NPOS * 16;                            // 16 MB
    float* Vp   = Kp + (size_t)16 * NPOS * 16;                            // 16 MB
    float* eg_i = Vp + (size_t)16 * NPOS * 16;                            // 1 MB
    float* eg_o = eg_i + (size_t)NPOS * 16;                               // 1 MB
    float* va   = eg_o + (size_t)NPOS * 16;                               // 16 MB

    // aliases (lifetime-checked): Etab/Gtab/B3t overlay dead e_hl region
    float* Etab = (float*)base;                                           // 1 MB
    float* Gtab = Etab + (size_t)2 * 8 * NPOS;                            // 1 MB
    unsigned short* B3t = (unsigned short*)(base + 2 * 1024 * 1024 + 256 * 1024);
    unsigned short* B1t = (unsigned short*)va;                            // dead before attn
    unsigned short* B2t = B1t + (size_t)2 * 448 * 128;

    ln_kernel<<<NPOS / 4, 256, 0, stream>>>(e, ln_w, ln_b, e_hl);

    pack_qkv_w<<<224, 256, 0, stream>>>(w_qkv_in, w_eg_in, B1t);
    pack_qkv_w<<<224, 256, 0, stream>>>(w_qkv_o,  w_eg_o,  B2t);

    gemm_qkv_kernel<<<dim3(128, 7, 2), 256, 0, stream>>>(
        e_hl, B1t, B2t, b_qkv_in, b_eg_in, b_qkv_o, b_eg_o,
        Qp, Kp, Vp, eg_i, eg_o);

    pack_o_w<<<128, 256, 0, stream>>>(w_o, B3t);   // e_hl dead now

    tables_kernel<<<128, 256, 0, stream>>>(eg_i, eg_o, mask, Etab, Gtab);

    attn_kernel<<<dim3(128, 8, 2), 256, 0, stream>>>(
        Qp, Kp, Vp, Etab, Gtab, va);

    gemm_out_kernel<<<dim3(256, 2), 256, 0, stream>>>(va, B3t, b_o, out);
}

// Round 6
// 241.449 us; speedup vs baseline: 2.3457x; 1.0717x over previous
//
#include <hip/hip_runtime.h>
#include <hip/hip_bf16.h>

// B=1, N=128, C=128, H=8, D=16. SCALE=0.25. All I/O fp32.
// GEMMs: bf16 MFMA, split-bf16 3-term (C = Ah@Bh + Al@Bh + Ah@Bl).
// Q/K/V stored as split-half planes: Qp[(br*8+h)*2+half][p][8] f32 (half: d<8 / d>=8),
// written via LDS-transpose epilogue -> fully coalesced float4 stores.
// ws (74.7 MB): e_hl ushort[16384][256] (aliased later: Etab/Gtab/B3t),
//   Qp/Kp/Vp f32[16][2][16384][8] (16MB each), eg_i/eg_o f32[16384][16],
//   va f32[16384][256] (B1t/B2t alias start, dead before attn).

#define NPOS 16384
#define CDIM 128

typedef __attribute__((ext_vector_type(8))) short bf16x8;
typedef __attribute__((ext_vector_type(4))) float f32x4;

static __device__ __forceinline__ unsigned short f2bf(float x) {
    union { float f; unsigned int u; } v; v.f = x;
    unsigned int u = v.u;
    unsigned int r = u + 0x7FFFu + ((u >> 16) & 1u);   // RNE
    return (unsigned short)(r >> 16);
}
static __device__ __forceinline__ float bf2f(unsigned short h) {
    union { float f; unsigned int u; } v; v.u = ((unsigned int)h) << 16; return v.f;
}

// ---------------- LayerNorm: wave-per-row, no LDS ----------------
__global__ __launch_bounds__(256) void ln_kernel(
    const float* __restrict__ e,
    const float* __restrict__ w,
    const float* __restrict__ b,
    unsigned short* __restrict__ e_hl)
{
    const int t = threadIdx.x;
    const int lane = t & 63;
    const int row = blockIdx.x * 4 + (t >> 6);
    float2 x = *(const float2*)(e + (size_t)row * CDIM + lane * 2);
    float s = x.x + x.y, s2 = x.x * x.x + x.y * x.y;
    #pragma unroll
    for (int off = 1; off < 64; off <<= 1) {
        s  += __shfl_xor(s,  off, 64);
        s2 += __shfl_xor(s2, off, 64);
    }
    float m = s * (1.f / 128.f);
    float v = s2 * (1.f / 128.f) - m * m;
    float sc = rsqrtf(v + 1e-5f);
    float2 wv = *(const float2*)(w + lane * 2);
    float2 bv = *(const float2*)(b + lane * 2);
    float y0 = (x.x - m) * sc * wv.x + bv.x;
    float y1 = (x.y - m) * sc * wv.y + bv.y;
    unsigned short h0 = f2bf(y0), h1 = f2bf(y1);
    ushort2 hi = {h0, h1};
    ushort2 lo = {f2bf(y0 - bf2f(h0)), f2bf(y1 - bf2f(h1))};
    *(ushort2*)(e_hl + (size_t)row * 256 + lane * 2)       = hi;
    *(ushort2*)(e_hl + (size_t)row * 256 + 128 + lane * 2) = lo;
}

// ---------------- Weight packs ----------------
__global__ __launch_bounds__(256) void pack_qkv_w(
    const float* __restrict__ wq, const float* __restrict__ we,
    unsigned short* __restrict__ Bt)
{
    int idx = blockIdx.x * 256 + threadIdx.x;    // n*128 + k
    int n = idx >> 7, k = idx & 127;
    float v = 0.f;
    if (n < 384) v = wq[(size_t)k * 384 + n];
    else if (n < 400) v = we[(size_t)k * 16 + (n - 384)];
    unsigned short hi = f2bf(v);
    Bt[idx] = hi;
    Bt[448 * 128 + idx] = f2bf(v - bf2f(hi));
}

__global__ __launch_bounds__(256) void pack_o_w(
    const float* __restrict__ wo, unsigned short* __restrict__ Bt)
{
    int idx = blockIdx.x * 256 + threadIdx.x;    // n*256 + k
    int n = idx >> 8, k = idx & 255;
    float v = wo[(size_t)k * 128 + n];
    unsigned short hi = f2bf(v);
    Bt[idx] = hi;
    Bt[128 * 256 + idx] = f2bf(v - bf2f(hi));
}

// ---------------- MFMA GEMM: qkv+eg, LDS-transpose epilogue ----------------
// grid(128, 7, 2), 256 thr. Tile 128(M) x 64(N). K=128.
// by 0,1: Q halves; 2,3: K; 4,5: V; 6: eg.
__global__ __launch_bounds__(256) void gemm_qkv_kernel(
    const unsigned short* __restrict__ e_hl,
    const unsigned short* __restrict__ B1t, const unsigned short* __restrict__ B2t,
    const float* __restrict__ bq_i, const float* __restrict__ be_i,
    const float* __restrict__ bq_o, const float* __restrict__ be_o,
    float* __restrict__ Qp, float* __restrict__ Kp, float* __restrict__ Vp,
    float* __restrict__ eg_i, float* __restrict__ eg_o)
{
    const int t = threadIdx.x;
    const int wave = t >> 6, lane = t & 63;
    const int m = lane & 15, q = lane >> 4;
    const int W0blk = blockIdx.x * 128;
    const int W0 = W0blk + wave * 32;
    const int by = blockIdx.y;
    const int N0 = by * 64;
    const int br = blockIdx.z;
    const unsigned short* Bt = br ? B2t : B1t;
    const float* bias_qkv = br ? bq_o : bq_i;
    const float* bias_eg  = br ? be_o : be_i;
    float* eg = br ? eg_o : eg_i;

    __shared__ float Ts[128][66];

    f32x4 acc[2][4];
    #pragma unroll
    for (int a = 0; a < 2; ++a)
        #pragma unroll
        for (int c = 0; c < 4; ++c) acc[a][c] = (f32x4){0.f, 0.f, 0.f, 0.f};

    const unsigned short* arow0 = e_hl + (size_t)(W0 + m) * 256;
    const unsigned short* arow1 = e_hl + (size_t)(W0 + 16 + m) * 256;
    const unsigned short* bcol[4];
    #pragma unroll
    for (int ns = 0; ns < 4; ++ns)
        bcol[ns] = Bt + (size_t)(N0 + ns * 16 + m) * 128;

    #pragma unroll
    for (int kc = 0; kc < 4; ++kc) {
        const int ko = kc * 32 + q * 8;
        bf16x8 a0h = *(const bf16x8*)(arow0 + ko);
        bf16x8 a0l = *(const bf16x8*)(arow0 + 128 + ko);
        bf16x8 a1h = *(const bf16x8*)(arow1 + ko);
        bf16x8 a1l = *(const bf16x8*)(arow1 + 128 + ko);
        bf16x8 bh[4], bl[4];
        #pragma unroll
        for (int ns = 0; ns < 4; ++ns) {
            bh[ns] = *(const bf16x8*)(bcol[ns] + ko);
            bl[ns] = *(const bf16x8*)(bcol[ns] + 448 * 128 + ko);
        }
        #pragma unroll
        for (int ns = 0; ns < 4; ++ns) {
            acc[0][ns] = __builtin_amdgcn_mfma_f32_16x16x32_bf16(a0h, bh[ns], acc[0][ns], 0, 0, 0);
            acc[1][ns] = __builtin_amdgcn_mfma_f32_16x16x32_bf16(a1h, bh[ns], acc[1][ns], 0, 0, 0);
        }
        #pragma unroll
        for (int ns = 0; ns < 4; ++ns) {
            acc[0][ns] = __builtin_amdgcn_mfma_f32_16x16x32_bf16(a0l, bh[ns], acc[0][ns], 0, 0, 0);
            acc[1][ns] = __builtin_amdgcn_mfma_f32_16x16x32_bf16(a1l, bh[ns], acc[1][ns], 0, 0, 0);
        }
        #pragma unroll
        for (int ns = 0; ns < 4; ++ns) {
            acc[0][ns] = __builtin_amdgcn_mfma_f32_16x16x32_bf16(a0h, bl[ns], acc[0][ns], 0, 0, 0);
            acc[1][ns] = __builtin_amdgcn_mfma_f32_16x16x32_bf16(a1h, bl[ns], acc[1][ns], 0, 0, 0);
        }
    }

    // stage tile (bias + Q-scale applied) into LDS
    #pragma unroll
    for (int ms = 0; ms < 2; ++ms) {
        #pragma unroll
        for (int ns = 0; ns < 4; ++ns) {
            const int lc = ns * 16 + m;
            const int col = N0 + lc;
            if (col < 400) {
                const float bias = (col < 384) ? bias_qkv[col] : bias_eg[col - 384];
                const float scale = (col < 128) ? 0.25f : 1.f;
                #pragma unroll
                for (int r = 0; r < 4; ++r) {
                    const int lr = wave * 32 + ms * 16 + q * 4 + r;
                    Ts[lr][lc] = (acc[ms][ns][r] + bias) * scale;
                }
            }
        }
    }
    __syncthreads();

    if (by < 6) {
        const int qsel = by >> 1, half = by & 1;
        float* Pbase = qsel == 0 ? Qp : (qsel == 1 ? Kp : Vp);
        #pragma unroll
        for (int it = 0; it < 8; ++it) {
            const int g = it * 256 + t;           // 0..2047
            const int hh = g >> 8;
            const int rem = g & 255;
            const int r128 = rem >> 1, sub = rem & 1;
            float4 val;
            val.x = Ts[r128][(sub * 4 + 0) * 8 + hh];
            val.y = Ts[r128][(sub * 4 + 1) * 8 + hh];
            val.z = Ts[r128][(sub * 4 + 2) * 8 + hh];
            val.w = Ts[r128][(sub * 4 + 3) * 8 + hh];
            size_t dst = (((size_t)(br * 8 + hh) * 2 + half) * NPOS + (W0blk + r128)) * 8 + sub * 4;
            *(float4*)(Pbase + dst) = val;
        }
    } else {
        #pragma unroll
        for (int it = 0; it < 2; ++it) {
            const int g = it * 256 + t;           // 0..511
            const int r128 = g >> 2, q4 = g & 3;
            float4 val;
            val.x = Ts[r128][q4 * 4 + 0];
            val.y = Ts[r128][q4 * 4 + 1];
            val.z = Ts[r128][q4 * 4 + 2];
            val.w = Ts[r128][q4 * 4 + 3];
            *(float4*)(eg + (size_t)(W0blk + r128) * 16 + q4 * 4) = val;
        }
    }
}

// ---------------- MFMA GEMM: output projection ----------------
// grid(256, 2), 256 thr. Tile 64(M) x 64(N), wave owns 16 rows. K=256.
__global__ __launch_bounds__(256) void gemm_out_kernel(
    const float* __restrict__ va,
    const unsigned short* __restrict__ B3t,
    const float* __restrict__ bias,
    float* __restrict__ out)
{
    const int t = threadIdx.x;
    const int wave = t >> 6, lane = t & 63;
    const int m = lane & 15, q = lane >> 4;
    const int W0 = blockIdx.x * 64 + wave * 16;
    const int N0 = blockIdx.y * 64;

    f32x4 acc[4];
    #pragma unroll
    for (int c = 0; c < 4; ++c) acc[c] = (f32x4){0.f, 0.f, 0.f, 0.f};

    const float* arow = va + (size_t)(W0 + m) * 256;
    const unsigned short* bcol[4];
    #pragma unroll
    for (int ns = 0; ns < 4; ++ns)
        bcol[ns] = B3t + (size_t)(N0 + ns * 16 + m) * 256;

    #pragma unroll 2
    for (int kc = 0; kc < 8; ++kc) {
        const int ko = kc * 32 + q * 8;
        const float4* ap = (const float4*)(arow + ko);
        float4 f0 = ap[0], f1 = ap[1];
        float xs[8] = {f0.x, f0.y, f0.z, f0.w, f1.x, f1.y, f1.z, f1.w};
        bf16x8 ah, al;
        #pragma unroll
        for (int jj = 0; jj < 8; ++jj) {
            unsigned short h = f2bf(xs[jj]);
            ah[jj] = (short)h;
            al[jj] = (short)f2bf(xs[jj] - bf2f(h));
        }
        bf16x8 bh[4], bl[4];
        #pragma unroll
        for (int ns = 0; ns < 4; ++ns) {
            bh[ns] = *(const bf16x8*)(bcol[ns] + ko);
            bl[ns] = *(const bf16x8*)(bcol[ns] + 128 * 256 + ko);
        }
        #pragma unroll
        for (int ns = 0; ns < 4; ++ns)
            acc[ns] = __builtin_amdgcn_mfma_f32_16x16x32_bf16(ah, bh[ns], acc[ns], 0, 0, 0);
        #pragma unroll
        for (int ns = 0; ns < 4; ++ns)
            acc[ns] = __builtin_amdgcn_mfma_f32_16x16x32_bf16(al, bh[ns], acc[ns], 0, 0, 0);
        #pragma unroll
        for (int ns = 0; ns < 4; ++ns)
            acc[ns] = __builtin_amdgcn_mfma_f32_16x16x32_bf16(ah, bl[ns], acc[ns], 0, 0, 0);
    }

    #pragma unroll
    for (int ns = 0; ns < 4; ++ns) {
        const int col = N0 + ns * 16 + m;
        #pragma unroll
        for (int r = 0; r < 4; ++r) {
            const int row = W0 + q * 4 + r;
            out[(size_t)row * 128 + col] = acc[ns][r] + bias[col];
        }
    }
}

// ---------------- Bias/gate tables ----------------
__global__ __launch_bounds__(256) void tables_kernel(
    const float* __restrict__ eg_in, const float* __restrict__ eg_out,
    const float* __restrict__ mask,
    float* __restrict__ Etab, float* __restrict__ Gtab)
{
    int flat = blockIdx.x * 256 + threadIdx.x;   // 0..32767
    int br = flat >> 14;
    int p  = flat & 16383;
    const float* eg = br ? eg_out : eg_in;
    const float4* row = (const float4*)(eg + (size_t)p * 16);
    float4 r0 = row[0], r1 = row[1], r2 = row[2], r3 = row[3];
    float m = mask[p];
    float E[8] = {r0.x, r0.y, r0.z, r0.w, r1.x, r1.y, r1.z, r1.w};
    float G[8] = {r2.x, r2.y, r2.z, r2.w, r3.x, r3.y, r3.z, r3.w};
    int i, k;
    if (br == 0) { i = p >> 7; k = p & 127; }
    else         { k = p >> 7; i = p & 127; }
    int dst = i * 128 + k;
    #pragma unroll
    for (int h = 0; h < 8; ++h) {
        size_t off = (size_t)(br * 8 + h) * NPOS + dst;
        Etab[off] = E[h] + m;
        Gtab[off] = 1.f / (1.f + __expf(-(G[h] + m)));
    }
}

// ---------------- Fused triangle attention v3 (split-half planes) ----------------
__global__ __launch_bounds__(256) void attn_kernel(
    const float* __restrict__ Qp, const float* __restrict__ Kp,
    const float* __restrict__ Vp,
    const float* __restrict__ Etab, const float* __restrict__ Gtab,
    float* __restrict__ va)
{
    const int j  = blockIdx.x;
    const int h  = blockIdx.y;
    const int br = blockIdx.z;
    const int t = threadIdx.x;
    const size_t pl = (size_t)(br * 8 + h);
    const float* __restrict__ Qh[2] = { Qp + (pl * 2 + 0) * (size_t)NPOS * 8,
                                        Qp + (pl * 2 + 1) * (size_t)NPOS * 8 };
    const float* __restrict__ Kh[2] = { Kp + (pl * 2 + 0) * (size_t)NPOS * 8,
                                        Kp + (pl * 2 + 1) * (size_t)NPOS * 8 };
    const float* __restrict__ Vh[2] = { Vp + (pl * 2 + 0) * (size_t)NPOS * 8,
                                        Vp + (pl * 2 + 1) * (size_t)NPOS * 8 };
    const float* __restrict__ Eb = Etab + pl * NPOS;
    const float* __restrict__ Gb = Gtab + pl * NPOS;

    __shared__ float Ks[128][20];
    __shared__ float Vs[128][20];

    #pragma unroll
    for (int it = 0; it < 2; ++it) {
        int v = t + it * 256;            // 0..511
        int k = v >> 2, dq = v & 3;      // dq: which float4 of the 16
        size_t p = br ? ((size_t)k * 128 + j) : ((size_t)j * 128 + k);
        int half = dq >> 1, off = (dq & 1) * 4;
        float4 kv = *(const float4*)(Kh[half] + p * 8 + off);
        float4 vv = *(const float4*)(Vh[half] + p * 8 + off);
        *(float4*)&Ks[k][dq * 4] = kv;
        *(float4*)&Vs[k][dq * 4] = vv;
    }
    __syncthreads();

    const int c  = t & 3;
    const int i0 = (t >> 2) * 2;

    float4 q0[4], q1[4];
    {
        size_t p0 = (size_t)(i0 * 128 + j), p1 = (size_t)((i0 + 1) * 128 + j);
        #pragma unroll
        for (int x = 0; x < 4; ++x) {
            q0[x] = *(const float4*)(Qh[x >> 1] + p0 * 8 + (x & 1) * 4);
            q1[x] = *(const float4*)(Qh[x >> 1] + p1 * 8 + (x & 1) * 4);
        }
    }

    float s[2][32];
    #pragma unroll
    for (int kk = 0; kk < 8; ++kk) {
        float4 e0 = *(const float4*)&Eb[(size_t)i0 * 128 + 16 * kk + 4 * c];
        float4 e1 = *(const float4*)&Eb[(size_t)(i0 + 1) * 128 + 16 * kk + 4 * c];
        s[0][kk * 4 + 0] = e0.x; s[0][kk * 4 + 1] = e0.y;
        s[0][kk * 4 + 2] = e0.z; s[0][kk * 4 + 3] = e0.w;
        s[1][kk * 4 + 0] = e1.x; s[1][kk * 4 + 1] = e1.y;
        s[1][kk * 4 + 2] = e1.z; s[1][kk * 4 + 3] = e1.w;
    }

    #pragma unroll
    for (int kk = 0; kk < 8; ++kk) {
        #pragma unroll
        for (int cc = 0; cc < 4; ++cc) {
            const int k = 16 * kk + 4 * c + cc;
            const float4* Kr = (const float4*)&Ks[k][0];
            float d0 = 0.f, d1 = 0.f;
            #pragma unroll
            for (int x = 0; x < 4; ++x) {
                float4 kv = Kr[x];
                d0 += q0[x].x * kv.x + q0[x].y * kv.y + q0[x].z * kv.z + q0[x].w * kv.w;
                d1 += q1[x].x * kv.x + q1[x].y * kv.y + q1[x].z * kv.z + q1[x].w * kv.w;
            }
            s[0][kk * 4 + cc] += d0;
            s[1][kk * 4 + cc] += d1;
        }
    }

    float mx0 = -1e30f, mx1 = -1e30f;
    #pragma unroll
    for (int x = 0; x < 32; ++x) { mx0 = fmaxf(mx0, s[0][x]); mx1 = fmaxf(mx1, s[1][x]); }
    mx0 = fmaxf(mx0, __shfl_xor(mx0, 1)); mx0 = fmaxf(mx0, __shfl_xor(mx0, 2));
    mx1 = fmaxf(mx1, __shfl_xor(mx1, 1)); mx1 = fmaxf(mx1, __shfl_xor(mx1, 2));
    float sm0 = 0.f, sm1 = 0.f;
    #pragma unroll
    for (int x = 0; x < 32; ++x) {
        float p0 = __expf(s[0][x] - mx0); s[0][x] = p0; sm0 += p0;
        float p1 = __expf(s[1][x] - mx1); s[1][x] = p1; sm1 += p1;
    }
    sm0 += __shfl_xor(sm0, 1); sm0 += __shfl_xor(sm0, 2);
    sm1 += __shfl_xor(sm1, 1); sm1 += __shfl_xor(sm1, 2);
    const float inv0 = 1.f / sm0, inv1 = 1.f / sm1;

    #pragma unroll
    for (int kk = 0; kk < 8; ++kk) {
        float4 g0 = *(const float4*)&Gb[(size_t)i0 * 128 + 16 * kk + 4 * c];
        float4 g1 = *(const float4*)&Gb[(size_t)(i0 + 1) * 128 + 16 * kk + 4 * c];
        s[0][kk * 4 + 0] *= inv0 * g0.x; s[0][kk * 4 + 1] *= inv0 * g0.y;
        s[0][kk * 4 + 2] *= inv0 * g0.z; s[0][kk * 4 + 3] *= inv0 * g0.w;
        s[1][kk * 4 + 0] *= inv1 * g1.x; s[1][kk * 4 + 1] *= inv1 * g1.y;
        s[1][kk * 4 + 2] *= inv1 * g1.z; s[1][kk * 4 + 3] *= inv1 * g1.w;
    }

    float acc0[16], acc1[16];
    #pragma unroll
    for (int d = 0; d < 16; ++d) { acc0[d] = 0.f; acc1[d] = 0.f; }
    #pragma unroll
    for (int kk = 0; kk < 8; ++kk) {
        #pragma unroll
        for (int cc = 0; cc < 4; ++cc) {
            const int k = 16 * kk + 4 * c + cc;
            const float4* Vr = (const float4*)&Vs[k][0];
            const float p0 = s[0][kk * 4 + cc];
            const float p1 = s[1][kk * 4 + cc];
            #pragma unroll
            for (int x = 0; x < 4; ++x) {
                float4 vv = Vr[x];
                acc0[x * 4 + 0] += p0 * vv.x; acc0[x * 4 + 1] += p0 * vv.y;
                acc0[x * 4 + 2] += p0 * vv.z; acc0[x * 4 + 3] += p0 * vv.w;
                acc1[x * 4 + 0] += p1 * vv.x; acc1[x * 4 + 1] += p1 * vv.y;
                acc1[x * 4 + 2] += p1 * vv.z; acc1[x * 4 + 3] += p1 * vv.w;
            }
        }
    }
    #pragma unroll
    for (int d = 0; d < 16; ++d) {
        acc0[d] += __shfl_xor(acc0[d], 1); acc0[d] += __shfl_xor(acc0[d], 2);
        acc1[d] += __shfl_xor(acc1[d], 1); acc1[d] += __shfl_xor(acc1[d], 2);
    }

    {
        size_t base0 = ((size_t)(i0 * 128 + j)) * 256 + br * 8 + h;
        size_t base1 = base0 + 128 * 256;
        #pragma unroll
        for (int x = 0; x < 4; ++x) {
            int d = 4 * c + x;
            va[base0 + (size_t)d * 16] = acc0[d];
            va[base1 + (size_t)d * 16] = acc1[d];
        }
    }
}

extern "C" void kernel_launch(void* const* d_in, const int* in_sizes, int n_in,
                              void* d_out, int out_size, void* d_ws, size_t ws_size,
                              hipStream_t stream) {
    const float* e        = (const float*)d_in[0];
    const float* mask     = (const float*)d_in[1];
    const float* ln_w     = (const float*)d_in[2];
    const float* ln_b     = (const float*)d_in[3];
    const float* w_qkv_in = (const float*)d_in[4];
    const float* b_qkv_in = (const float*)d_in[5];
    const float* w_eg_in  = (const float*)d_in[6];
    const float* b_eg_in  = (const float*)d_in[7];
    const float* w_qkv_o  = (const float*)d_in[8];
    const float* b_qkv_o  = (const float*)d_in[9];
    const float* w_eg_o   = (const float*)d_in[10];
    const float* b_eg_o   = (const float*)d_in[11];
    const float* w_o      = (const float*)d_in[12];
    const float* b_o      = (const float*)d_in[13];
    float* out = (float*)d_out;

    char* base = (char*)d_ws;
    unsigned short* e_hl = (unsigned short*)base;                         // 8.39 MB
    float* Qp   = (float*)(base + (size_t)NPOS * 256 * 2);                // 16 MB
    float* Kp   = Qp + (size_t)16 * NPOS * 16;                            // 16 MB
    float* Vp   = Kp + (size_t)16 * NPOS * 16;                            // 16 MB
    float* eg_i = Vp + (size_t)16 * NPOS * 16;                            // 1 MB
    float* eg_o = eg_i + (size_t)NPOS * 16;                               // 1 MB
    float* va   = eg_o + (size_t)NPOS * 16;                               // 16 MB

    // aliases (lifetime-checked): Etab/Gtab/B3t overlay dead e_hl region
    float* Etab = (float*)base;                                           // 1 MB
    float* Gtab = Etab + (size_t)2 * 8 * NPOS;                            // 1 MB
    unsigned short* B3t = (unsigned short*)(base + 2 * 1024 * 1024 + 256 * 1024);
    unsigned short* B1t = (unsigned short*)va;                            // dead before attn
    unsigned short* B2t = B1t + (size_t)2 * 448 * 128;

    ln_kernel<<<NPOS / 4, 256, 0, stream>>>(e, ln_w, ln_b, e_hl);

    pack_qkv_w<<<224, 256, 0, stream>>>(w_qkv_in, w_eg_in, B1t);
    pack_qkv_w<<<224, 256, 0, stream>>>(w_qkv_o,  w_eg_o,  B2t);

    gemm_qkv_kernel<<<dim3(128, 7, 2), 256, 0, stream>>>(
        e_hl, B1t, B2t, b_qkv_in, b_eg_in, b_qkv_o, b_eg_o,
        Qp, Kp, Vp, eg_i, eg_o);

    pack_o_w<<<128, 256, 0, stream>>>(w_o, B3t);   // e_hl dead now

    tables_kernel<<<128, 256, 0, stream>>>(eg_i, eg_o, mask, Etab, Gtab);

    attn_kernel<<<dim3(128, 8, 2), 256, 0, stream>>>(
        Qp, Kp, Vp, Etab, Gtab, va);

    gemm_out_kernel<<<dim3(256, 2), 256, 0, stream>>>(va, B3t, b_o, out);
}

// Round 7
// 217.586 us; speedup vs baseline: 2.6029x; 1.1097x over previous
//
#include <hip/hip_runtime.h>
#include <hip/hip_bf16.h>

// B=1, N=128, C=128, H=8, D=16. SCALE=0.25. All I/O fp32.
// GEMMs + attention QK^T/AV via bf16 MFMA, split-bf16 hi/lo for fp32 quality.
// Plane arrays (ushort, hi and lo separate), rows of 16 ushorts (32B):
//   Q planes: j-major (row j*128+i holds Q[i*128+j]) for BOTH branches.
//   K/V planes: br=0 i-major (row p holds K[p]); br=1 j-major.
//   => attn always reads row (j*128 + idx), contiguous.
// va layout: row p' = j*128+i, col k' = (br*8+h)*16 + d  (64B-line writes).
// ws (77.6 MB): e_hl ushort[16384][256] (aliased later: Etab/Gtab/B3t),
//   QTh,QTl,KH,KL,VH,VL ushort[16][16384][16] (8MB each),
//   eg_i/eg_o f32[16384][16], va f32[16384][256] (B1t/B2t alias va start).

#define NPOS 16384
#define CDIM 128

typedef __attribute__((ext_vector_type(8))) short bf16x8;
typedef __attribute__((ext_vector_type(8))) unsigned short u16x8;
typedef __attribute__((ext_vector_type(4))) float f32x4;

#define MFMA16(a, b, c) __builtin_amdgcn_mfma_f32_16x16x32_bf16((a), (b), (c), 0, 0, 0)

static __device__ __forceinline__ unsigned short f2bf(float x) {
    union { float f; unsigned int u; } v; v.f = x;
    unsigned int u = v.u;
    unsigned int r = u + 0x7FFFu + ((u >> 16) & 1u);   // RNE
    return (unsigned short)(r >> 16);
}
static __device__ __forceinline__ float bf2f(unsigned short h) {
    union { float f; unsigned int u; } v; v.u = ((unsigned int)h) << 16; return v.f;
}

// ---------------- LayerNorm: wave-per-row, no LDS ----------------
__global__ __launch_bounds__(256) void ln_kernel(
    const float* __restrict__ e,
    const float* __restrict__ w,
    const float* __restrict__ b,
    unsigned short* __restrict__ e_hl)
{
    const int t = threadIdx.x;
    const int lane = t & 63;
    const int row = blockIdx.x * 4 + (t >> 6);
    float2 x = *(const float2*)(e + (size_t)row * CDIM + lane * 2);
    float s = x.x + x.y, s2 = x.x * x.x + x.y * x.y;
    #pragma unroll
    for (int off = 1; off < 64; off <<= 1) {
        s  += __shfl_xor(s,  off, 64);
        s2 += __shfl_xor(s2, off, 64);
    }
    float m = s * (1.f / 128.f);
    float v = s2 * (1.f / 128.f) - m * m;
    float sc = rsqrtf(v + 1e-5f);
    float2 wv = *(const float2*)(w + lane * 2);
    float2 bv = *(const float2*)(b + lane * 2);
    float y0 = (x.x - m) * sc * wv.x + bv.x;
    float y1 = (x.y - m) * sc * wv.y + bv.y;
    unsigned short h0 = f2bf(y0), h1 = f2bf(y1);
    ushort2 hi = {h0, h1};
    ushort2 lo = {f2bf(y0 - bf2f(h0)), f2bf(y1 - bf2f(h1))};
    *(ushort2*)(e_hl + (size_t)row * 256 + lane * 2)       = hi;
    *(ushort2*)(e_hl + (size_t)row * 256 + 128 + lane * 2) = lo;
}

// ---------------- Weight packs ----------------
__global__ __launch_bounds__(256) void pack_qkv_w(
    const float* __restrict__ wq, const float* __restrict__ we,
    unsigned short* __restrict__ Bt)
{
    int idx = blockIdx.x * 256 + threadIdx.x;    // n*128 + k
    int n = idx >> 7, k = idx & 127;
    float v = 0.f;
    if (n < 384) v = wq[(size_t)k * 384 + n];
    else if (n < 400) v = we[(size_t)k * 16 + (n - 384)];
    unsigned short hi = f2bf(v);
    Bt[idx] = hi;
    Bt[448 * 128 + idx] = f2bf(v - bf2f(hi));
}

// w_o packed in k' = (br*8+h)*16 + d ordering (orig k = d*16 + br*8 + h).
__global__ __launch_bounds__(256) void pack_o_w(
    const float* __restrict__ wo, unsigned short* __restrict__ Bt)
{
    int idx = blockIdx.x * 256 + threadIdx.x;    // n*256 + kp
    int n = idx >> 8, kp = idx & 255;
    int d = kp & 15, pl = kp >> 4;
    int k = d * 16 + pl;
    float v = wo[(size_t)k * 128 + n];
    unsigned short hi = f2bf(v);
    Bt[idx] = hi;
    Bt[128 * 256 + idx] = f2bf(v - bf2f(hi));
}

// ---------------- MFMA GEMM: qkv+eg -> bf16 hi/lo plane arrays ----------------
// grid(128, 7, 2), 256 thr. Tile 128(M) x 64(N). K=128.
// by 0,1: Q d-halves; 2,3: K; 4,5: V; 6: eg (f32).
__global__ __launch_bounds__(256) void gemm_qkv_kernel(
    const unsigned short* __restrict__ e_hl,
    const unsigned short* __restrict__ B1t, const unsigned short* __restrict__ B2t,
    const float* __restrict__ bq_i, const float* __restrict__ be_i,
    const float* __restrict__ bq_o, const float* __restrict__ be_o,
    unsigned short* __restrict__ QTh, unsigned short* __restrict__ QTl,
    unsigned short* __restrict__ KH,  unsigned short* __restrict__ KL,
    unsigned short* __restrict__ VH,  unsigned short* __restrict__ VL,
    float* __restrict__ eg_i, float* __restrict__ eg_o)
{
    const int t = threadIdx.x;
    const int wave = t >> 6, lane = t & 63;
    const int m = lane & 15, q = lane >> 4;
    const int bx = blockIdx.x;
    const int W0 = bx * 128 + wave * 32;
    const int by = blockIdx.y;
    const int N0 = by * 64;
    const int br = blockIdx.z;
    const unsigned short* Bt = br ? B2t : B1t;
    const float* bias_qkv = br ? bq_o : bq_i;
    const float* bias_eg  = br ? be_o : be_i;
    float* eg = br ? eg_o : eg_i;

    __shared__ float Ts[128][66];

    f32x4 acc[2][4];
    #pragma unroll
    for (int a = 0; a < 2; ++a)
        #pragma unroll
        for (int c = 0; c < 4; ++c) acc[a][c] = (f32x4){0.f, 0.f, 0.f, 0.f};

    const unsigned short* arow0 = e_hl + (size_t)(W0 + m) * 256;
    const unsigned short* arow1 = e_hl + (size_t)(W0 + 16 + m) * 256;
    const unsigned short* bcol[4];
    #pragma unroll
    for (int ns = 0; ns < 4; ++ns)
        bcol[ns] = Bt + (size_t)(N0 + ns * 16 + m) * 128;

    #pragma unroll
    for (int kc = 0; kc < 4; ++kc) {
        const int ko = kc * 32 + q * 8;
        bf16x8 a0h = *(const bf16x8*)(arow0 + ko);
        bf16x8 a0l = *(const bf16x8*)(arow0 + 128 + ko);
        bf16x8 a1h = *(const bf16x8*)(arow1 + ko);
        bf16x8 a1l = *(const bf16x8*)(arow1 + 128 + ko);
        bf16x8 bh[4], bl[4];
        #pragma unroll
        for (int ns = 0; ns < 4; ++ns) {
            bh[ns] = *(const bf16x8*)(bcol[ns] + ko);
            bl[ns] = *(const bf16x8*)(bcol[ns] + 448 * 128 + ko);
        }
        #pragma unroll
        for (int ns = 0; ns < 4; ++ns) {
            acc[0][ns] = MFMA16(a0h, bh[ns], acc[0][ns]);
            acc[1][ns] = MFMA16(a1h, bh[ns], acc[1][ns]);
        }
        #pragma unroll
        for (int ns = 0; ns < 4; ++ns) {
            acc[0][ns] = MFMA16(a0l, bh[ns], acc[0][ns]);
            acc[1][ns] = MFMA16(a1l, bh[ns], acc[1][ns]);
        }
        #pragma unroll
        for (int ns = 0; ns < 4; ++ns) {
            acc[0][ns] = MFMA16(a0h, bl[ns], acc[0][ns]);
            acc[1][ns] = MFMA16(a1h, bl[ns], acc[1][ns]);
        }
    }

    // stage tile (bias + Q-scale applied) into LDS
    #pragma unroll
    for (int ms = 0; ms < 2; ++ms) {
        #pragma unroll
        for (int ns = 0; ns < 4; ++ns) {
            const int lc = ns * 16 + m;
            const int col = N0 + lc;
            if (col < 400) {
                const float bias = (col < 384) ? bias_qkv[col] : bias_eg[col - 384];
                const float scale = (col < 128) ? 0.25f : 1.f;
                #pragma unroll
                for (int r = 0; r < 4; ++r) {
                    const int lr = wave * 32 + ms * 16 + q * 4 + r;
                    Ts[lr][lc] = (acc[ms][ns][r] + bias) * scale;
                }
            }
        }
    }
    __syncthreads();

    if (by < 6) {
        const int qsel = by >> 1, dhalf = by & 1;
        unsigned short* dstH = (qsel == 0) ? QTh : (qsel == 1 ? KH : VH);
        unsigned short* dstL = (qsel == 0) ? QTl : (qsel == 1 ? KL : VL);
        const bool jmajor = (qsel == 0) || (br == 1);
        #pragma unroll
        for (int it = 0; it < 4; ++it) {
            int item = it * 256 + t;        // 0..1023: (hh, lr)
            int hh = item >> 7, lr = item & 127;
            u16x8 hi, lo;
            #pragma unroll
            for (int dd = 0; dd < 8; ++dd) {
                float v = Ts[lr][dd * 8 + hh];
                unsigned short hv = f2bf(v);
                hi[dd] = hv;
                lo[dd] = f2bf(v - bf2f(hv));
            }
            int row = jmajor ? (lr * 128 + bx) : (bx * 128 + lr);
            size_t addr = ((size_t)(br * 8 + hh) * NPOS + row) * 16 + dhalf * 8;
            *(u16x8*)(dstH + addr) = hi;
            *(u16x8*)(dstL + addr) = lo;
        }
    } else {
        #pragma unroll
        for (int it = 0; it < 2; ++it) {
            const int g = it * 256 + t;           // 0..511
            const int r128 = g >> 2, q4 = g & 3;
            float4 val;
            val.x = Ts[r128][q4 * 4 + 0];
            val.y = Ts[r128][q4 * 4 + 1];
            val.z = Ts[r128][q4 * 4 + 2];
            val.w = Ts[r128][q4 * 4 + 3];
            *(float4*)(eg + (size_t)(bx * 128 + r128) * 16 + q4 * 4) = val;
        }
    }
}

// ---------------- MFMA GEMM: output projection (va in p'/k' order) ----------------
// grid(256, 2), 256 thr. Tile 64(M) x 64(N). K=256. Row-permuted C store.
__global__ __launch_bounds__(256) void gemm_out_kernel(
    const float* __restrict__ va,
    const unsigned short* __restrict__ B3t,
    const float* __restrict__ bias,
    float* __restrict__ out)
{
    const int t = threadIdx.x;
    const int wave = t >> 6, lane = t & 63;
    const int m = lane & 15, q = lane >> 4;
    const int W0 = blockIdx.x * 64 + wave * 16;
    const int N0 = blockIdx.y * 64;

    f32x4 acc[4];
    #pragma unroll
    for (int c = 0; c < 4; ++c) acc[c] = (f32x4){0.f, 0.f, 0.f, 0.f};

    const float* arow = va + (size_t)(W0 + m) * 256;
    const unsigned short* bcol[4];
    #pragma unroll
    for (int ns = 0; ns < 4; ++ns)
        bcol[ns] = B3t + (size_t)(N0 + ns * 16 + m) * 256;

    #pragma unroll 2
    for (int kc = 0; kc < 8; ++kc) {
        const int ko = kc * 32 + q * 8;
        const float4* ap = (const float4*)(arow + ko);
        float4 f0 = ap[0], f1 = ap[1];
        float xs[8] = {f0.x, f0.y, f0.z, f0.w, f1.x, f1.y, f1.z, f1.w};
        bf16x8 ah, al;
        #pragma unroll
        for (int jj = 0; jj < 8; ++jj) {
            unsigned short h = f2bf(xs[jj]);
            ah[jj] = (short)h;
            al[jj] = (short)f2bf(xs[jj] - bf2f(h));
        }
        bf16x8 bh[4], bl[4];
        #pragma unroll
        for (int ns = 0; ns < 4; ++ns) {
            bh[ns] = *(const bf16x8*)(bcol[ns] + ko);
            bl[ns] = *(const bf16x8*)(bcol[ns] + 128 * 256 + ko);
        }
        #pragma unroll
        for (int ns = 0; ns < 4; ++ns) acc[ns] = MFMA16(ah, bh[ns], acc[ns]);
        #pragma unroll
        for (int ns = 0; ns < 4; ++ns) acc[ns] = MFMA16(al, bh[ns], acc[ns]);
        #pragma unroll
        for (int ns = 0; ns < 4; ++ns) acc[ns] = MFMA16(ah, bl[ns], acc[ns]);
    }

    #pragma unroll
    for (int ns = 0; ns < 4; ++ns) {
        const int col = N0 + ns * 16 + m;
        #pragma unroll
        for (int r = 0; r < 4; ++r) {
            const int prow = W0 + q * 4 + r;                 // p' = j*128+i
            const int orow = ((prow & 127) << 7) | (prow >> 7);  // i*128+j
            out[(size_t)orow * 128 + col] = acc[ns][r] + bias[col];
        }
    }
}

// ---------------- Bias/gate tables ----------------
__global__ __launch_bounds__(256) void tables_kernel(
    const float* __restrict__ eg_in, const float* __restrict__ eg_out,
    const float* __restrict__ mask,
    float* __restrict__ Etab, float* __restrict__ Gtab)
{
    int flat = blockIdx.x * 256 + threadIdx.x;   // 0..32767
    int br = flat >> 14;
    int p  = flat & 16383;
    const float* eg = br ? eg_out : eg_in;
    const float4* row = (const float4*)(eg + (size_t)p * 16);
    float4 r0 = row[0], r1 = row[1], r2 = row[2], r3 = row[3];
    float m = mask[p];
    float E[8] = {r0.x, r0.y, r0.z, r0.w, r1.x, r1.y, r1.z, r1.w};
    float G[8] = {r2.x, r2.y, r2.z, r2.w, r3.x, r3.y, r3.z, r3.w};
    int i, k;
    if (br == 0) { i = p >> 7; k = p & 127; }
    else         { k = p >> 7; i = p & 127; }
    int dst = i * 128 + k;
    #pragma unroll
    for (int h = 0; h < 8; ++h) {
        size_t off = (size_t)(br * 8 + h) * NPOS + dst;
        Etab[off] = E[h] + m;
        Gtab[off] = 1.f / (1.f + __expf(-(G[h] + m)));
    }
}

// ---------------- MFMA fused triangle attention v4 ----------------
// grid (j=128, h=8, br=2), 256 thr = 4 waves, wave owns 32-row strip.
// S = Qh(Kh+Kl) + QlKh via 16x16x32 MFMA (K>=16 lanes zeroed); softmax in regs;
// P (bf16, gated+normalized) -> LDS -> A-frags; AV = P@(Vh+Vl) via MFMA.
__global__ __launch_bounds__(256) void attn_kernel(
    const unsigned short* __restrict__ QTh, const unsigned short* __restrict__ QTl,
    const unsigned short* __restrict__ KH,  const unsigned short* __restrict__ KL,
    const unsigned short* __restrict__ VH,  const unsigned short* __restrict__ VL,
    const float* __restrict__ Etab, const float* __restrict__ Gtab,
    float* __restrict__ va)
{
    const int j = blockIdx.x, h = blockIdx.y, br = blockIdx.z;
    const int t = threadIdx.x;
    const int wave = t >> 6, lane = t & 63;
    const int m = lane & 15, q = lane >> 4;
    const int plane = br * 8 + h;
    const size_t pbase = (size_t)plane * NPOS;
    const unsigned short* Qh_g = QTh + (pbase + (size_t)j * 128) * 16;
    const unsigned short* Ql_g = QTl + (pbase + (size_t)j * 128) * 16;
    const unsigned short* Kh_g = KH  + (pbase + (size_t)j * 128) * 16;
    const unsigned short* Kl_g = KL  + (pbase + (size_t)j * 128) * 16;
    const unsigned short* Vh_g = VH  + (pbase + (size_t)j * 128) * 16;
    const unsigned short* Vl_g = VL  + (pbase + (size_t)j * 128) * 16;
    const float* __restrict__ Eb = Etab + pbase;
    const float* __restrict__ Gb = Gtab + pbase;

    __shared__ unsigned short Vth[16 * 136];
    __shared__ unsigned short Vtl[16 * 136];
    __shared__ unsigned short Pl[128 * 136];

    // stage V transposed (hi/lo) into LDS
    #pragma unroll
    for (int it = 0; it < 2; ++it) {
        int item = it * 256 + t;        // 0..511
        int hl = item >> 8;
        int rem = item & 255;
        int key = rem >> 1, ch = rem & 1;
        const unsigned short* src = (hl ? Vl_g : Vh_g) + (size_t)key * 16 + ch * 8;
        u16x8 v = *(const u16x8*)src;
        unsigned short* dst = hl ? Vtl : Vth;
        #pragma unroll
        for (int dd = 0; dd < 8; ++dd)
            dst[(ch * 8 + dd) * 136 + key] = v[dd];
    }

    const int strip = wave * 32;
    const bf16x8 zero8 = {};

    // Q A-frags (direct from global; q>=2 lanes = zero K-half)
    bf16x8 aQh[2], aQl[2];
    #pragma unroll
    for (int mt = 0; mt < 2; ++mt) {
        const size_t off = (size_t)(strip + mt * 16 + m) * 16 + (q & 1) * 8;
        aQh[mt] = (q < 2) ? *(const bf16x8*)(Qh_g + off) : zero8;
        aQl[mt] = (q < 2) ? *(const bf16x8*)(Ql_g + off) : zero8;
    }

    // S tiles
    f32x4 S[2][8];
    #pragma unroll
    for (int nt = 0; nt < 8; ++nt) {
        const size_t koff = (size_t)(nt * 16 + m) * 16 + (q & 1) * 8;
        bf16x8 bKh = (q < 2) ? *(const bf16x8*)(Kh_g + koff) : zero8;
        bf16x8 bKl = (q < 2) ? *(const bf16x8*)(Kl_g + koff) : zero8;
        #pragma unroll
        for (int mt = 0; mt < 2; ++mt) {
            f32x4 a = (f32x4){0.f, 0.f, 0.f, 0.f};
            a = MFMA16(aQh[mt], bKl, a);
            a = MFMA16(aQl[mt], bKh, a);
            a = MFMA16(aQh[mt], bKh, a);
            S[mt][nt] = a;
        }
    }

    // E bias (C-layout: row = q*4+r, col = m)
    #pragma unroll
    for (int mt = 0; mt < 2; ++mt)
        #pragma unroll
        for (int r = 0; r < 4; ++r) {
            const int i = strip + mt * 16 + q * 4 + r;
            #pragma unroll
            for (int nt = 0; nt < 8; ++nt)
                S[mt][nt][r] += Eb[(size_t)i * 128 + nt * 16 + m];
        }

    // softmax (rows fully within wave) + gate + P -> LDS (bf16)
    #pragma unroll
    for (int mt = 0; mt < 2; ++mt)
        #pragma unroll
        for (int r = 0; r < 4; ++r) {
            float v = -1e30f;
            #pragma unroll
            for (int nt = 0; nt < 8; ++nt) v = fmaxf(v, S[mt][nt][r]);
            v = fmaxf(v, __shfl_xor(v, 1)); v = fmaxf(v, __shfl_xor(v, 2));
            v = fmaxf(v, __shfl_xor(v, 4)); v = fmaxf(v, __shfl_xor(v, 8));
            float s = 0.f;
            #pragma unroll
            for (int nt = 0; nt < 8; ++nt) {
                float p = __expf(S[mt][nt][r] - v);
                S[mt][nt][r] = p;
                s += p;
            }
            s += __shfl_xor(s, 1); s += __shfl_xor(s, 2);
            s += __shfl_xor(s, 4); s += __shfl_xor(s, 8);
            const float inv = 1.f / s;
            const int i = strip + mt * 16 + q * 4 + r;
            #pragma unroll
            for (int nt = 0; nt < 8; ++nt) {
                float g = Gb[(size_t)i * 128 + nt * 16 + m];
                Pl[i * 136 + nt * 16 + m] = f2bf(S[mt][nt][r] * inv * g);
            }
        }

    __syncthreads();   // Vt ready (and P via lgkm drain)

    // AV = P @ (Vh + Vl)
    f32x4 av[2] = {(f32x4){0.f, 0.f, 0.f, 0.f}, (f32x4){0.f, 0.f, 0.f, 0.f}};
    #pragma unroll
    for (int kc = 0; kc < 4; ++kc) {
        const int off = kc * 32 + q * 8;
        bf16x8 bVh = *(const bf16x8*)&Vth[m * 136 + off];
        bf16x8 bVl = *(const bf16x8*)&Vtl[m * 136 + off];
        #pragma unroll
        for (int mt = 0; mt < 2; ++mt) {
            bf16x8 aP = *(const bf16x8*)&Pl[(strip + mt * 16 + m) * 136 + off];
            av[mt] = MFMA16(aP, bVl, av[mt]);
            av[mt] = MFMA16(aP, bVh, av[mt]);
        }
    }

    // store va' (row p' = j*128+i, col k' = plane*16 + d): 64B-line coalesced
    #pragma unroll
    for (int mt = 0; mt < 2; ++mt)
        #pragma unroll
        for (int r = 0; r < 4; ++r) {
            const int i = strip + mt * 16 + q * 4 + r;
            va[((size_t)(j * 128 + i)) * 256 + plane * 16 + m] = av[mt][r];
        }
}

extern "C" void kernel_launch(void* const* d_in, const int* in_sizes, int n_in,
                              void* d_out, int out_size, void* d_ws, size_t ws_size,
                              hipStream_t stream) {
    const float* e        = (const float*)d_in[0];
    const float* mask     = (const float*)d_in[1];
    const float* ln_w     = (const float*)d_in[2];
    const float* ln_b     = (const float*)d_in[3];
    const float* w_qkv_in = (const float*)d_in[4];
    const float* b_qkv_in = (const float*)d_in[5];
    const float* w_eg_in  = (const float*)d_in[6];
    const float* b_eg_in  = (const float*)d_in[7];
    const float* w_qkv_o  = (const float*)d_in[8];
    const float* b_qkv_o  = (const float*)d_in[9];
    const float* w_eg_o   = (const float*)d_in[10];
    const float* b_eg_o   = (const float*)d_in[11];
    const float* w_o      = (const float*)d_in[12];
    const float* b_o      = (const float*)d_in[13];
    float* out = (float*)d_out;

    char* base = (char*)d_ws;
    const size_t PLANE = (size_t)16 * NPOS * 16;                      // ushorts per array
    unsigned short* e_hl = (unsigned short*)base;                     // 8.39 MB
    unsigned short* QTh = (unsigned short*)(base + (size_t)NPOS * 256 * 2);
    unsigned short* QTl = QTh + PLANE;
    unsigned short* KH  = QTl + PLANE;
    unsigned short* KL  = KH + PLANE;
    unsigned short* VH  = KL + PLANE;
    unsigned short* VL  = VH + PLANE;
    float* eg_i = (float*)(VL + PLANE);                               // 1 MB
    float* eg_o = eg_i + (size_t)NPOS * 16;                           // 1 MB
    float* va   = eg_o + (size_t)NPOS * 16;                           // 16 MB

    // aliases (lifetime-checked): Etab/Gtab/B3t overlay dead e_hl region
    float* Etab = (float*)base;                                       // 1 MB
    float* Gtab = Etab + (size_t)2 * 8 * NPOS;                        // 1 MB
    unsigned short* B3t = (unsigned short*)(base + 2 * 1024 * 1024 + 256 * 1024);
    unsigned short* B1t = (unsigned short*)va;                        // dead before attn
    unsigned short* B2t = B1t + (size_t)2 * 448 * 128;

    ln_kernel<<<NPOS / 4, 256, 0, stream>>>(e, ln_w, ln_b, e_hl);

    pack_qkv_w<<<224, 256, 0, stream>>>(w_qkv_in, w_eg_in, B1t);
    pack_qkv_w<<<224, 256, 0, stream>>>(w_qkv_o,  w_eg_o,  B2t);

    gemm_qkv_kernel<<<dim3(128, 7, 2), 256, 0, stream>>>(
        e_hl, B1t, B2t, b_qkv_in, b_eg_in, b_qkv_o, b_eg_o,
        QTh, QTl, KH, KL, VH, VL, eg_i, eg_o);

    pack_o_w<<<128, 256, 0, stream>>>(w_o, B3t);   // e_hl dead now

    tables_kernel<<<128, 256, 0, stream>>>(eg_i, eg_o, mask, Etab, Gtab);

    attn_kernel<<<dim3(128, 8, 2), 256, 0, stream>>>(
        QTh, QTl, KH, KL, VH, VL, Etab, Gtab, va);

    gemm_out_kernel<<<dim3(256, 2), 256, 0, stream>>>(va, B3t, b_o, out);
}

// Round 8
// 214.524 us; speedup vs baseline: 2.6401x; 1.0143x over previous
//
#include <hip/hip_runtime.h>
#include <hip/hip_bf16.h>

// B=1, N=128, C=128, H=8, D=16. SCALE=0.25. All I/O fp32.
// GEMMs + attention QK^T/AV via bf16 MFMA, split-bf16 hi/lo for fp32 quality.
// Plane arrays (ushort, hi/lo separate): [plane=br*8+h][dhalf][p][8] (16B rows).
// gemm_qkv writes ALL sub-planes i-major (dense, coalesced). transpose_kernel
// then in-place converts to j-major the sub-planes attn reads column-wise:
// Q (both br), K/V (br=1). attn reads row (j*128+idx) contiguously everywhere.
// va layout: row p' = j*128+i, col k' = (br*8+h)*16 + d (64B-line writes);
// gemm_out un-permutes rows on store.
// ws (74.6 MB): e_hl ushort[16384][256] (aliased later: Etab/Gtab/B3t),
//   QTh,QTl,KH,KL,VH,VL ushort[16][2][16384][8] (8MB each),
//   eg_i/eg_o f32[16384][16], va f32[16384][256] (B1t/B2t alias va start).

#define NPOS 16384
#define CDIM 128

typedef __attribute__((ext_vector_type(8))) short bf16x8;
typedef __attribute__((ext_vector_type(8))) unsigned short u16x8;
typedef __attribute__((ext_vector_type(4))) float f32x4;

#define MFMA16(a, b, c) __builtin_amdgcn_mfma_f32_16x16x32_bf16((a), (b), (c), 0, 0, 0)

static __device__ __forceinline__ unsigned short f2bf(float x) {
    union { float f; unsigned int u; } v; v.f = x;
    unsigned int u = v.u;
    unsigned int r = u + 0x7FFFu + ((u >> 16) & 1u);   // RNE
    return (unsigned short)(r >> 16);
}
static __device__ __forceinline__ float bf2f(unsigned short h) {
    union { float f; unsigned int u; } v; v.u = ((unsigned int)h) << 16; return v.f;
}

// ---------------- LayerNorm: wave-per-row, no LDS ----------------
__global__ __launch_bounds__(256) void ln_kernel(
    const float* __restrict__ e,
    const float* __restrict__ w,
    const float* __restrict__ b,
    unsigned short* __restrict__ e_hl)
{
    const int t = threadIdx.x;
    const int lane = t & 63;
    const int row = blockIdx.x * 4 + (t >> 6);
    float2 x = *(const float2*)(e + (size_t)row * CDIM + lane * 2);
    float s = x.x + x.y, s2 = x.x * x.x + x.y * x.y;
    #pragma unroll
    for (int off = 1; off < 64; off <<= 1) {
        s  += __shfl_xor(s,  off, 64);
        s2 += __shfl_xor(s2, off, 64);
    }
    float m = s * (1.f / 128.f);
    float v = s2 * (1.f / 128.f) - m * m;
    float sc = rsqrtf(v + 1e-5f);
    float2 wv = *(const float2*)(w + lane * 2);
    float2 bv = *(const float2*)(b + lane * 2);
    float y0 = (x.x - m) * sc * wv.x + bv.x;
    float y1 = (x.y - m) * sc * wv.y + bv.y;
    unsigned short h0 = f2bf(y0), h1 = f2bf(y1);
    ushort2 hi = {h0, h1};
    ushort2 lo = {f2bf(y0 - bf2f(h0)), f2bf(y1 - bf2f(h1))};
    *(ushort2*)(e_hl + (size_t)row * 256 + lane * 2)       = hi;
    *(ushort2*)(e_hl + (size_t)row * 256 + 128 + lane * 2) = lo;
}

// ---------------- Weight packs ----------------
__global__ __launch_bounds__(256) void pack_qkv_w(
    const float* __restrict__ wq, const float* __restrict__ we,
    unsigned short* __restrict__ Bt)
{
    int idx = blockIdx.x * 256 + threadIdx.x;    // n*128 + k
    int n = idx >> 7, k = idx & 127;
    float v = 0.f;
    if (n < 384) v = wq[(size_t)k * 384 + n];
    else if (n < 400) v = we[(size_t)k * 16 + (n - 384)];
    unsigned short hi = f2bf(v);
    Bt[idx] = hi;
    Bt[448 * 128 + idx] = f2bf(v - bf2f(hi));
}

// w_o packed in k' = (br*8+h)*16 + d ordering (orig k = d*16 + br*8 + h).
__global__ __launch_bounds__(256) void pack_o_w(
    const float* __restrict__ wo, unsigned short* __restrict__ Bt)
{
    int idx = blockIdx.x * 256 + threadIdx.x;    // n*256 + kp
    int n = idx >> 8, kp = idx & 255;
    int d = kp & 15, pl = kp >> 4;
    int k = d * 16 + pl;
    float v = wo[(size_t)k * 128 + n];
    unsigned short hi = f2bf(v);
    Bt[idx] = hi;
    Bt[128 * 256 + idx] = f2bf(v - bf2f(hi));
}

// ---------------- MFMA GEMM: qkv+eg -> bf16 hi/lo sub-planes (i-major) --------
// grid(128, 7, 2), 256 thr. Tile 128(M) x 64(N). K=128.
// by 0,1: Q d-halves; 2,3: K; 4,5: V; 6: eg (f32).
__global__ __launch_bounds__(256) void gemm_qkv_kernel(
    const unsigned short* __restrict__ e_hl,
    const unsigned short* __restrict__ B1t, const unsigned short* __restrict__ B2t,
    const float* __restrict__ bq_i, const float* __restrict__ be_i,
    const float* __restrict__ bq_o, const float* __restrict__ be_o,
    unsigned short* __restrict__ QTh, unsigned short* __restrict__ QTl,
    unsigned short* __restrict__ KH,  unsigned short* __restrict__ KL,
    unsigned short* __restrict__ VH,  unsigned short* __restrict__ VL,
    float* __restrict__ eg_i, float* __restrict__ eg_o)
{
    const int t = threadIdx.x;
    const int wave = t >> 6, lane = t & 63;
    const int m = lane & 15, q = lane >> 4;
    const int bx = blockIdx.x;
    const int W0 = bx * 128 + wave * 32;
    const int by = blockIdx.y;
    const int N0 = by * 64;
    const int br = blockIdx.z;
    const unsigned short* Bt = br ? B2t : B1t;
    const float* bias_qkv = br ? bq_o : bq_i;
    const float* bias_eg  = br ? be_o : be_i;
    float* eg = br ? eg_o : eg_i;

    __shared__ float Ts[128][66];

    f32x4 acc[2][4];
    #pragma unroll
    for (int a = 0; a < 2; ++a)
        #pragma unroll
        for (int c = 0; c < 4; ++c) acc[a][c] = (f32x4){0.f, 0.f, 0.f, 0.f};

    const unsigned short* arow0 = e_hl + (size_t)(W0 + m) * 256;
    const unsigned short* arow1 = e_hl + (size_t)(W0 + 16 + m) * 256;
    const unsigned short* bcol[4];
    #pragma unroll
    for (int ns = 0; ns < 4; ++ns)
        bcol[ns] = Bt + (size_t)(N0 + ns * 16 + m) * 128;

    #pragma unroll
    for (int kc = 0; kc < 4; ++kc) {
        const int ko = kc * 32 + q * 8;
        bf16x8 a0h = *(const bf16x8*)(arow0 + ko);
        bf16x8 a0l = *(const bf16x8*)(arow0 + 128 + ko);
        bf16x8 a1h = *(const bf16x8*)(arow1 + ko);
        bf16x8 a1l = *(const bf16x8*)(arow1 + 128 + ko);
        bf16x8 bh[4], bl[4];
        #pragma unroll
        for (int ns = 0; ns < 4; ++ns) {
            bh[ns] = *(const bf16x8*)(bcol[ns] + ko);
            bl[ns] = *(const bf16x8*)(bcol[ns] + 448 * 128 + ko);
        }
        #pragma unroll
        for (int ns = 0; ns < 4; ++ns) {
            acc[0][ns] = MFMA16(a0h, bh[ns], acc[0][ns]);
            acc[1][ns] = MFMA16(a1h, bh[ns], acc[1][ns]);
        }
        #pragma unroll
        for (int ns = 0; ns < 4; ++ns) {
            acc[0][ns] = MFMA16(a0l, bh[ns], acc[0][ns]);
            acc[1][ns] = MFMA16(a1l, bh[ns], acc[1][ns]);
        }
        #pragma unroll
        for (int ns = 0; ns < 4; ++ns) {
            acc[0][ns] = MFMA16(a0h, bl[ns], acc[0][ns]);
            acc[1][ns] = MFMA16(a1h, bl[ns], acc[1][ns]);
        }
    }

    // stage tile (bias + Q-scale applied) into LDS
    #pragma unroll
    for (int ms = 0; ms < 2; ++ms) {
        #pragma unroll
        for (int ns = 0; ns < 4; ++ns) {
            const int lc = ns * 16 + m;
            const int col = N0 + lc;
            if (col < 400) {
                const float bias = (col < 384) ? bias_qkv[col] : bias_eg[col - 384];
                const float scale = (col < 128) ? 0.25f : 1.f;
                #pragma unroll
                for (int r = 0; r < 4; ++r) {
                    const int lr = wave * 32 + ms * 16 + q * 4 + r;
                    Ts[lr][lc] = (acc[ms][ns][r] + bias) * scale;
                }
            }
        }
    }
    __syncthreads();

    if (by < 6) {
        const int qsel = by >> 1, dhalf = by & 1;
        unsigned short* dstH = (qsel == 0) ? QTh : (qsel == 1 ? KH : VH);
        unsigned short* dstL = (qsel == 0) ? QTl : (qsel == 1 ? KL : VL);
        #pragma unroll
        for (int it = 0; it < 4; ++it) {
            int item = it * 256 + t;        // 0..1023: (hh, lr)
            int hh = item >> 7, lr = item & 127;
            u16x8 hi, lo;
            #pragma unroll
            for (int dd = 0; dd < 8; ++dd) {
                float v = Ts[lr][dd * 8 + hh];    // local col = dd*8+hh
                unsigned short hv = f2bf(v);
                hi[dd] = hv;
                lo[dd] = f2bf(v - bf2f(hv));
            }
            size_t addr = (((size_t)(br * 8 + hh) * 2 + dhalf) * NPOS
                           + (size_t)bx * 128 + lr) * 8;   // i-major, dense
            *(u16x8*)(dstH + addr) = hi;
            *(u16x8*)(dstL + addr) = lo;
        }
    } else {
        #pragma unroll
        for (int it = 0; it < 2; ++it) {
            const int g = it * 256 + t;           // 0..511
            const int r128 = g >> 2, q4 = g & 3;
            float4 val;
            val.x = Ts[r128][q4 * 4 + 0];
            val.y = Ts[r128][q4 * 4 + 1];
            val.z = Ts[r128][q4 * 4 + 2];
            val.w = Ts[r128][q4 * 4 + 3];
            *(float4*)(eg + (size_t)(bx * 128 + r128) * 16 + q4 * 4) = val;
        }
    }
}

// ---------------- In-place sub-plane transpose (i-major -> j-major) ----------
// Sub-plane = [128][128] matrix of 16B elements. grid(36, 128): x = tile pair
// (a<=b) of 16x16-element tiles, y = sub-plane selector:
//   0..31 QTh, 32..63 QTl, 64..79 KH(br=1), 80..95 KL, 96..111 VH, 112..127 VL.
__global__ __launch_bounds__(256) void transpose_kernel(
    unsigned short* __restrict__ QTh, unsigned short* __restrict__ QTl,
    unsigned short* __restrict__ KH,  unsigned short* __restrict__ KL,
    unsigned short* __restrict__ VH,  unsigned short* __restrict__ VL)
{
    const int s = blockIdx.y;
    unsigned short* base;
    int sub;
    if (s < 32)       { base = QTh; sub = s; }
    else if (s < 64)  { base = QTl; sub = s - 32; }
    else if (s < 80)  { base = KH;  sub = 16 + (s - 64); }
    else if (s < 96)  { base = KL;  sub = 16 + (s - 80); }
    else if (s < 112) { base = VH;  sub = 16 + (s - 96); }
    else              { base = VL;  sub = 16 + (s - 112); }
    unsigned short* P = base + (size_t)sub * NPOS * 8;

    int x = blockIdx.x, a = 0;
    while (x >= 8 - a) { x -= 8 - a; ++a; }
    const int b = a + x;

    __shared__ unsigned short T1[16][136];   // pad 8 -> 2-way max
    __shared__ unsigned short T2[16][136];

    const int t = threadIdx.x;
    const int r = t >> 4, c = t & 15;

    u16x8 v1 = *(const u16x8*)(P + ((size_t)(a * 16 + r) * 128 + b * 16 + c) * 8);
    *(u16x8*)&T1[r][c * 8] = v1;
    if (a != b) {
        u16x8 v2 = *(const u16x8*)(P + ((size_t)(b * 16 + r) * 128 + a * 16 + c) * 8);
        *(u16x8*)&T2[r][c * 8] = v2;
    }
    __syncthreads();

    u16x8 w1 = *(const u16x8*)&T1[c][r * 8];
    *(u16x8*)(P + ((size_t)(b * 16 + r) * 128 + a * 16 + c) * 8) = w1;
    if (a != b) {
        u16x8 w2 = *(const u16x8*)&T2[c][r * 8];
        *(u16x8*)(P + ((size_t)(a * 16 + r) * 128 + b * 16 + c) * 8) = w2;
    }
}

// ---------------- MFMA GEMM: output projection (va in p'/k' order) ----------------
// grid(256, 2), 256 thr. Tile 64(M) x 64(N). K=256. Row-permuted C store.
__global__ __launch_bounds__(256) void gemm_out_kernel(
    const float* __restrict__ va,
    const unsigned short* __restrict__ B3t,
    const float* __restrict__ bias,
    float* __restrict__ out)
{
    const int t = threadIdx.x;
    const int wave = t >> 6, lane = t & 63;
    const int m = lane & 15, q = lane >> 4;
    const int W0 = blockIdx.x * 64 + wave * 16;
    const int N0 = blockIdx.y * 64;

    f32x4 acc[4];
    #pragma unroll
    for (int c = 0; c < 4; ++c) acc[c] = (f32x4){0.f, 0.f, 0.f, 0.f};

    const float* arow = va + (size_t)(W0 + m) * 256;
    const unsigned short* bcol[4];
    #pragma unroll
    for (int ns = 0; ns < 4; ++ns)
        bcol[ns] = B3t + (size_t)(N0 + ns * 16 + m) * 256;

    #pragma unroll 2
    for (int kc = 0; kc < 8; ++kc) {
        const int ko = kc * 32 + q * 8;
        const float4* ap = (const float4*)(arow + ko);
        float4 f0 = ap[0], f1 = ap[1];
        float xs[8] = {f0.x, f0.y, f0.z, f0.w, f1.x, f1.y, f1.z, f1.w};
        bf16x8 ah, al;
        #pragma unroll
        for (int jj = 0; jj < 8; ++jj) {
            unsigned short h = f2bf(xs[jj]);
            ah[jj] = (short)h;
            al[jj] = (short)f2bf(xs[jj] - bf2f(h));
        }
        bf16x8 bh[4], bl[4];
        #pragma unroll
        for (int ns = 0; ns < 4; ++ns) {
            bh[ns] = *(const bf16x8*)(bcol[ns] + ko);
            bl[ns] = *(const bf16x8*)(bcol[ns] + 128 * 256 + ko);
        }
        #pragma unroll
        for (int ns = 0; ns < 4; ++ns) acc[ns] = MFMA16(ah, bh[ns], acc[ns]);
        #pragma unroll
        for (int ns = 0; ns < 4; ++ns) acc[ns] = MFMA16(al, bh[ns], acc[ns]);
        #pragma unroll
        for (int ns = 0; ns < 4; ++ns) acc[ns] = MFMA16(ah, bl[ns], acc[ns]);
    }

    #pragma unroll
    for (int ns = 0; ns < 4; ++ns) {
        const int col = N0 + ns * 16 + m;
        #pragma unroll
        for (int r = 0; r < 4; ++r) {
            const int prow = W0 + q * 4 + r;                 // p' = j*128+i
            const int orow = ((prow & 127) << 7) | (prow >> 7);  // i*128+j
            out[(size_t)orow * 128 + col] = acc[ns][r] + bias[col];
        }
    }
}

// ---------------- Bias/gate tables ----------------
__global__ __launch_bounds__(256) void tables_kernel(
    const float* __restrict__ eg_in, const float* __restrict__ eg_out,
    const float* __restrict__ mask,
    float* __restrict__ Etab, float* __restrict__ Gtab)
{
    int flat = blockIdx.x * 256 + threadIdx.x;   // 0..32767
    int br = flat >> 14;
    int p  = flat & 16383;
    const float* eg = br ? eg_out : eg_in;
    const float4* row = (const float4*)(eg + (size_t)p * 16);
    float4 r0 = row[0], r1 = row[1], r2 = row[2], r3 = row[3];
    float m = mask[p];
    float E[8] = {r0.x, r0.y, r0.z, r0.w, r1.x, r1.y, r1.z, r1.w};
    float G[8] = {r2.x, r2.y, r2.z, r2.w, r3.x, r3.y, r3.z, r3.w};
    int i, k;
    if (br == 0) { i = p >> 7; k = p & 127; }
    else         { k = p >> 7; i = p & 127; }
    int dst = i * 128 + k;
    #pragma unroll
    for (int h = 0; h < 8; ++h) {
        size_t off = (size_t)(br * 8 + h) * NPOS + dst;
        Etab[off] = E[h] + m;
        Gtab[off] = 1.f / (1.f + __expf(-(G[h] + m)));
    }
}

// ---------------- MFMA fused triangle attention v4 (split-half sub-planes) ---
// grid (j=128, h=8, br=2), 256 thr = 4 waves, wave owns 32-row strip.
__global__ __launch_bounds__(256) void attn_kernel(
    const unsigned short* __restrict__ QTh, const unsigned short* __restrict__ QTl,
    const unsigned short* __restrict__ KH,  const unsigned short* __restrict__ KL,
    const unsigned short* __restrict__ VH,  const unsigned short* __restrict__ VL,
    const float* __restrict__ Etab, const float* __restrict__ Gtab,
    float* __restrict__ va)
{
    const int j = blockIdx.x, h = blockIdx.y, br = blockIdx.z;
    const int t = threadIdx.x;
    const int wave = t >> 6, lane = t & 63;
    const int m = lane & 15, q = lane >> 4;
    const int plane = br * 8 + h;
    const size_t SP = (size_t)NPOS * 8;          // ushorts per sub-plane
    const size_t jb = (size_t)j * 128 * 8;
    const float* __restrict__ Eb = Etab + (size_t)plane * NPOS;
    const float* __restrict__ Gb = Gtab + (size_t)plane * NPOS;

    __shared__ unsigned short Vth[16 * 136];
    __shared__ unsigned short Vtl[16 * 136];
    __shared__ unsigned short Pl[128 * 136];

    // stage V transposed (hi/lo) into LDS
    #pragma unroll
    for (int it = 0; it < 2; ++it) {
        int item = it * 256 + t;        // 0..511
        int hl = item >> 8;
        int rem = item & 255;
        int key = rem >> 1, ch = rem & 1;
        const unsigned short* src = (hl ? VL : VH)
            + (size_t)(plane * 2 + ch) * SP + jb + (size_t)key * 8;
        u16x8 v = *(const u16x8*)src;
        unsigned short* dst = hl ? Vtl : Vth;
        #pragma unroll
        for (int dd = 0; dd < 8; ++dd)
            dst[(ch * 8 + dd) * 136 + key] = v[dd];
    }

    const int strip = wave * 32;
    const bf16x8 zero8 = {};
    const int hf = q & 1;
    const size_t qko = (size_t)(plane * 2 + hf) * SP + jb;

    // Q A-frags (direct from global; q>=2 lanes = zero K-half)
    bf16x8 aQh[2], aQl[2];
    #pragma unroll
    for (int mt = 0; mt < 2; ++mt) {
        const size_t off = qko + (size_t)(strip + mt * 16 + m) * 8;
        aQh[mt] = (q < 2) ? *(const bf16x8*)(QTh + off) : zero8;
        aQl[mt] = (q < 2) ? *(const bf16x8*)(QTl + off) : zero8;
    }

    // S tiles
    f32x4 S[2][8];
    #pragma unroll
    for (int nt = 0; nt < 8; ++nt) {
        const size_t koff = qko + (size_t)(nt * 16 + m) * 8;
        bf16x8 bKh = (q < 2) ? *(const bf16x8*)(KH + koff) : zero8;
        bf16x8 bKl = (q < 2) ? *(const bf16x8*)(KL + koff) : zero8;
        #pragma unroll
        for (int mt = 0; mt < 2; ++mt) {
            f32x4 a = (f32x4){0.f, 0.f, 0.f, 0.f};
            a = MFMA16(aQh[mt], bKl, a);
            a = MFMA16(aQl[mt], bKh, a);
            a = MFMA16(aQh[mt], bKh, a);
            S[mt][nt] = a;
        }
    }

    // E bias (C-layout: row = q*4+r, col = m)
    #pragma unroll
    for (int mt = 0; mt < 2; ++mt)
        #pragma unroll
        for (int r = 0; r < 4; ++r) {
            const int i = strip + mt * 16 + q * 4 + r;
            #pragma unroll
            for (int nt = 0; nt < 8; ++nt)
                S[mt][nt][r] += Eb[(size_t)i * 128 + nt * 16 + m];
        }

    // softmax (rows fully within wave) + gate + P -> LDS (bf16)
    #pragma unroll
    for (int mt = 0; mt < 2; ++mt)
        #pragma unroll
        for (int r = 0; r < 4; ++r) {
            float v = -1e30f;
            #pragma unroll
            for (int nt = 0; nt < 8; ++nt) v = fmaxf(v, S[mt][nt][r]);
            v = fmaxf(v, __shfl_xor(v, 1)); v = fmaxf(v, __shfl_xor(v, 2));
            v = fmaxf(v, __shfl_xor(v, 4)); v = fmaxf(v, __shfl_xor(v, 8));
            float s = 0.f;
            #pragma unroll
            for (int nt = 0; nt < 8; ++nt) {
                float p = __expf(S[mt][nt][r] - v);
                S[mt][nt][r] = p;
                s += p;
            }
            s += __shfl_xor(s, 1); s += __shfl_xor(s, 2);
            s += __shfl_xor(s, 4); s += __shfl_xor(s, 8);
            const float inv = 1.f / s;
            const int i = strip + mt * 16 + q * 4 + r;
            #pragma unroll
            for (int nt = 0; nt < 8; ++nt) {
                float g = Gb[(size_t)i * 128 + nt * 16 + m];
                Pl[i * 136 + nt * 16 + m] = f2bf(S[mt][nt][r] * inv * g);
            }
        }

    __syncthreads();   // Vt ready (and P via lgkm drain)

    // AV = P @ (Vh + Vl)
    f32x4 av[2] = {(f32x4){0.f, 0.f, 0.f, 0.f}, (f32x4){0.f, 0.f, 0.f, 0.f}};
    #pragma unroll
    for (int kc = 0; kc < 4; ++kc) {
        const int off = kc * 32 + q * 8;
        bf16x8 bVh = *(const bf16x8*)&Vth[m * 136 + off];
        bf16x8 bVl = *(const bf16x8*)&Vtl[m * 136 + off];
        #pragma unroll
        for (int mt = 0; mt < 2; ++mt) {
            bf16x8 aP = *(const bf16x8*)&Pl[(strip + mt * 16 + m) * 136 + off];
            av[mt] = MFMA16(aP, bVl, av[mt]);
            av[mt] = MFMA16(aP, bVh, av[mt]);
        }
    }

    // store va' (row p' = j*128+i, col k' = plane*16 + d): 64B-line coalesced
    #pragma unroll
    for (int mt = 0; mt < 2; ++mt)
        #pragma unroll
        for (int r = 0; r < 4; ++r) {
            const int i = strip + mt * 16 + q * 4 + r;
            va[((size_t)(j * 128 + i)) * 256 + plane * 16 + m] = av[mt][r];
        }
}

extern "C" void kernel_launch(void* const* d_in, const int* in_sizes, int n_in,
                              void* d_out, int out_size, void* d_ws, size_t ws_size,
                              hipStream_t stream) {
    const float* e        = (const float*)d_in[0];
    const float* mask     = (const float*)d_in[1];
    const float* ln_w     = (const float*)d_in[2];
    const float* ln_b     = (const float*)d_in[3];
    const float* w_qkv_in = (const float*)d_in[4];
    const float* b_qkv_in = (const float*)d_in[5];
    const float* w_eg_in  = (const float*)d_in[6];
    const float* b_eg_in  = (const float*)d_in[7];
    const float* w_qkv_o  = (const float*)d_in[8];
    const float* b_qkv_o  = (const float*)d_in[9];
    const float* w_eg_o   = (const float*)d_in[10];
    const float* b_eg_o   = (const float*)d_in[11];
    const float* w_o      = (const float*)d_in[12];
    const float* b_o      = (const float*)d_in[13];
    float* out = (float*)d_out;

    char* base = (char*)d_ws;
    const size_t PLANE = (size_t)16 * NPOS * 16;                      // ushorts per array
    unsigned short* e_hl = (unsigned short*)base;                     // 8.39 MB
    unsigned short* QTh = (unsigned short*)(base + (size_t)NPOS * 256 * 2);
    unsigned short* QTl = QTh + PLANE;
    unsigned short* KH  = QTl + PLANE;
    unsigned short* KL  = KH + PLANE;
    unsigned short* VH  = KL + PLANE;
    unsigned short* VL  = VH + PLANE;
    float* eg_i = (float*)(VL + PLANE);                               // 1 MB
    float* eg_o = eg_i + (size_t)NPOS * 16;                           // 1 MB
    float* va   = eg_o + (size_t)NPOS * 16;                           // 16 MB

    // aliases (lifetime-checked): Etab/Gtab/B3t overlay dead e_hl region
    float* Etab = (float*)base;                                       // 1 MB
    float* Gtab = Etab + (size_t)2 * 8 * NPOS;                        // 1 MB
    unsigned short* B3t = (unsigned short*)(base + 2 * 1024 * 1024 + 256 * 1024);
    unsigned short* B1t = (unsigned short*)va;                        // dead before attn
    unsigned short* B2t = B1t + (size_t)2 * 448 * 128;

    ln_kernel<<<NPOS / 4, 256, 0, stream>>>(e, ln_w, ln_b, e_hl);

    pack_qkv_w<<<224, 256, 0, stream>>>(w_qkv_in, w_eg_in, B1t);
    pack_qkv_w<<<224, 256, 0, stream>>>(w_qkv_o,  w_eg_o,  B2t);

    gemm_qkv_kernel<<<dim3(128, 7, 2), 256, 0, stream>>>(
        e_hl, B1t, B2t, b_qkv_in, b_eg_in, b_qkv_o, b_eg_o,
        QTh, QTl, KH, KL, VH, VL, eg_i, eg_o);

    transpose_kernel<<<dim3(36, 128), 256, 0, stream>>>(
        QTh, QTl, KH, KL, VH, VL);

    pack_o_w<<<128, 256, 0, stream>>>(w_o, B3t);   // e_hl dead now

    tables_kernel<<<128, 256, 0, stream>>>(eg_i, eg_o, mask, Etab, Gtab);

    attn_kernel<<<dim3(128, 8, 2), 256, 0, stream>>>(
        QTh, QTl, KH, KL, VH, VL, Etab, Gtab, va);

    gemm_out_kernel<<<dim3(256, 2), 256, 0, stream>>>(va, B3t, b_o, out);
}